// Round 4
// baseline (1213.500 us; speedup 1.0000x reference)
//
#include <hip/hip_runtime.h>

typedef unsigned int u32;
typedef unsigned long long u64;

#define BB 2
#define TT 4
#define NF 8            // B*T frames
#define RR 128          // rois
#define NSAMP 32        // num_sample
#define KK2 5           // max points per fine voxel
#define MAXV 50000
#define GX1 376
#define GY1 376
#define C1 141376       // GX1*GY1 (gz=1)
#define NC1 1131008     // NF*C1
#define GX2 752
#define GY2 752
#define GZ2 30
#define WPF 530160      // bitmap words per frame = GX2*GY2*GZ2/32
#define RBW 12          // roibm words per row (376 bits)
#define NPAD 262144
#define NMAXP 262144
#define MAXROWS 1536
#define RPT 6           // rows per thread in k_output (256*6 = 1536)
#define STN 2112        // status entries per scan (>= max tiles 2071)

#define PCX (-75.2f)
#define PCY (-75.2f)
#define PCZ (-2.0f)
#define VS1 0.4f
#define VSH 0.2f
#define VZ1 6.0f

// ---------------- workspace init ----------------
// z0,z1: zero segments; f2: 0xFF segment. Counts are in uint4 units.
__global__ void k_init(u32* z0, u32 n0, u32* z1, u32 n1, u32* f2, u32 n2)
{
    u32 tid = blockIdx.x * blockDim.x + threadIdx.x;
    u32 stride = gridDim.x * blockDim.x;
    uint4 zz = make_uint4(0u, 0u, 0u, 0u);
    uint4 fv = make_uint4(~0u, ~0u, ~0u, ~0u);
    for (u32 i = tid; i < n0; i += stride) ((uint4*)z0)[i] = zz;
    for (u32 i = tid; i < n1; i += stride) ((uint4*)z1)[i] = zz;
    for (u32 i = tid; i < n2; i += stride) ((uint4*)f2)[i] = fv;
}

// ---------------- fused: box params + roi raster + stage-1 point voxelize ----------------
// boxp layout per (f,r), 12 u32 words:
// 0:bx 1:by 2:cur_r^2 3:zmax (floats); 4:Qx 5:Qy 6:irad 7:Q1x 8:Q1y 9:irad2 (ints)
__global__ void k_roipts(const float* P, int n, const float* traj, const float* back,
                         const unsigned char* vlb, u32* boxp, u32* roibm, u32* pvid, u32* cnt1)
{
    int i = blockIdx.x * blockDim.x + threadIdx.x;
    if (i < NF * RR) {
        // detect valid_length storage: int32 (0/1 -> bytes at %4!=0 are 0) vs uint8/bool
        bool isU8 = false;
        for (int k = 1; k < 64; k++)
            if ((k & 3) && vlb[k]) isU8 = true;
        bool vl = isU8 ? (vlb[i] != 0) : (((const int*)vlb)[i] != 0);
        const float* tb = traj + i * 7;
        const float* bb = back + i * 7;
        float bx = vl ? (tb[0] + bb[0]) * 0.5f : bb[0];
        float by = vl ? (tb[1] + bb[1]) * 0.5f : bb[1];
        float bz = bb[2], dx = bb[3], dy = bb[4], dz = bb[5];
        float hx = dx * 0.5f, hy = dy * 0.5f;
        float r0 = sqrtf(hx * hx + hy * hy);
        float radf = ceilf(r0 * 1.1f / 0.4f);
        float curr = r0 * 1.1f;
        u32* bp = boxp + i * 12;
        int Qx = (int)floorf((bx - PCX) / VS1);
        int Qy = (int)floorf((by - PCY) / VS1);
        int ir = (int)radf;
        bp[0] = __float_as_uint(bx);
        bp[1] = __float_as_uint(by);
        bp[2] = __float_as_uint(curr * curr);
        bp[3] = __float_as_uint(bz + dz * 0.6f);
        bp[4] = (u32)Qx;
        bp[5] = (u32)Qy;
        bp[6] = (u32)ir;
        bp[7] = (u32)(int)floorf((bx - PCX) / VSH);
        bp[8] = (u32)(int)floorf((by - PCY) / VSH);
        bp[9] = (u32)(2 * ir);

        int f = i / RR;
        int xlo = Qx - ir + 1; if (xlo < 0) xlo = 0;
        int xhi = Qx + ir - 1; if (xhi > GX1 - 1) xhi = GX1 - 1;
        int ylo = Qy - ir + 1; if (ylo < 0) ylo = 0;
        int yhi = Qy + ir - 1; if (yhi > GY1 - 1) yhi = GY1 - 1;
        if (xlo <= xhi && ylo <= yhi) {
            int w0 = xlo >> 5, w1 = xhi >> 5;
            for (int cy = ylo; cy <= yhi; cy++) {
                u32* row = roibm + (size_t)f * (GY1 * RBW) + cy * RBW;
                for (int w = w0; w <= w1; w++) {
                    int lo = xlo - (w << 5); if (lo < 0) lo = 0;
                    int hi = xhi - (w << 5); if (hi > 31) hi = 31;
                    u32 m = (hi == 31 ? 0xFFFFFFFFu : ((1u << (hi + 1)) - 1u)) & ~((1u << lo) - 1u);
                    atomicOr(&row[w], m);
                }
            }
        }
    }
    if (i < n) {
        const float* p = P + (size_t)i * 6;
        float bsf = p[0], x = p[1], y = p[2], z = p[3], tt = p[5];
        u32 g = 0xFFFFFFFFu;
        int b = (int)bsf;
        int t = (int)floorf(tt * 10.0f + 0.5f);
        if (bsf == (float)b && b >= 0 && b < BB && t >= 0 && t < TT &&
            fabsf(tt - 0.1f * (float)t) < 0.001f) {
            float fx = floorf((x - PCX) / VS1);
            float fy = floorf((y - PCY) / VS1);
            float fz = floorf((z - PCZ) / VZ1);
            if (fx >= 0.f && fx < (float)GX1 && fy >= 0.f && fy < (float)GY1 && fz == 0.f) {
                g = (u32)((b * TT + t) * C1) + (u32)fy * GX1 + (u32)fx;
            }
        }
        pvid[i] = g;
        if (g != 0xFFFFFFFFu) atomicAdd(&cnt1[g], 1u);
    }
}

// ---------------- single-pass decoupled-lookback exclusive scan ----------------
// MODE 0: in=counts -> lo:prefix(count) hi:prefix(count!=0)
// MODE 1: in=u32    -> lo:prefix(in)
// MODE 3: in=bitmap -> lo:prefix(popcount)
// status word: state(2b)<<62 | hi(28b)<<28 | lo(28b); all running sums < 2^28.
// Ticket-ordered tile assignment guarantees forward progress.
template <int MODE>
__global__ void __launch_bounds__(256) k_scan_lb(const u32* in, u32* out_lo, u32* out_hi,
                                                 u64* status, u32* ticket, int n, int ntiles)
{
    __shared__ u64 sh[256];
    __shared__ u64 excl_sh;
    __shared__ u32 vt_sh;
    int t = threadIdx.x;
    if (t == 0) vt_sh = atomicAdd(ticket, 1u);
    __syncthreads();
    int vt = (int)vt_sh;
    int base = vt * 2048 + t * 8;
    u32 v[8];
    if (base + 8 <= n) {
        uint4 a = *(const uint4*)(in + base);
        uint4 bq = *(const uint4*)(in + base + 4);
        v[0] = a.x; v[1] = a.y; v[2] = a.z; v[3] = a.w;
        v[4] = bq.x; v[5] = bq.y; v[6] = bq.z; v[7] = bq.w;
    } else {
        #pragma unroll
        for (int e = 0; e < 8; e++) { int i = base + e; v[e] = (i < n) ? in[i] : 0u; }
    }
    u64 pref[8]; u64 sum = 0;
    #pragma unroll
    for (int e = 0; e < 8; e++) {
        u64 val;
        if (MODE == 0)      val = (u64)v[e] | ((u64)(v[e] != 0u) << 32);
        else if (MODE == 1) val = v[e];
        else                val = (u32)__popc(v[e]);
        pref[e] = sum; sum += val;
    }
    sh[t] = sum;
    __syncthreads();
    for (int off = 1; off < 256; off <<= 1) {
        u64 y = (t >= off) ? sh[t - off] : 0;
        __syncthreads();
        sh[t] += y;
        __syncthreads();
    }
    u64 texcl = sh[t] - sum;
    if (t == 255) {
        u64 total = sh[255];
        u64 tlo = total & 0xFFFFFFFFull, thi = total >> 32;
        u64 excl = 0;
        if (vt == 0) {
            __hip_atomic_store(&status[0], (2ull << 62) | (thi << 28) | tlo,
                               __ATOMIC_RELEASE, __HIP_MEMORY_SCOPE_AGENT);
        } else {
            __hip_atomic_store(&status[vt], (1ull << 62) | (thi << 28) | tlo,
                               __ATOMIC_RELEASE, __HIP_MEMORY_SCOPE_AGENT);
            u64 elo = 0, ehi = 0;
            int idx = vt - 1;
            while (true) {
                u64 s = __hip_atomic_load(&status[idx], __ATOMIC_ACQUIRE, __HIP_MEMORY_SCOPE_AGENT);
                u64 st = s >> 62;
                if (st == 0) { __builtin_amdgcn_s_sleep(1); continue; }
                elo += s & 0xFFFFFFFull;
                ehi += (s >> 28) & 0xFFFFFFFull;
                if (st == 2ull) break;
                idx--;
            }
            excl = elo | (ehi << 32);
            __hip_atomic_store(&status[vt], (2ull << 62) | ((thi + ehi) << 28) | (tlo + elo),
                               __ATOMIC_RELEASE, __HIP_MEMORY_SCOPE_AGENT);
        }
        excl_sh = excl;
        if (vt == ntiles - 1) {
            out_lo[n] = (u32)((excl & 0xFFFFFFFFull) + tlo);
            if (MODE == 0) out_hi[n] = (u32)((excl >> 32) + thi);
        }
    }
    __syncthreads();
    u64 eb = excl_sh;
    if (base + 8 <= n) {
        u32 lo_a[8], hi_a[8];
        #pragma unroll
        for (int e = 0; e < 8; e++) {
            u64 x = eb + texcl + pref[e];
            lo_a[e] = (u32)x; hi_a[e] = (u32)(x >> 32);
        }
        *(uint4*)(out_lo + base)     = make_uint4(lo_a[0], lo_a[1], lo_a[2], lo_a[3]);
        *(uint4*)(out_lo + base + 4) = make_uint4(lo_a[4], lo_a[5], lo_a[6], lo_a[7]);
        if (MODE == 0) {
            *(uint4*)(out_hi + base)     = make_uint4(hi_a[0], hi_a[1], hi_a[2], hi_a[3]);
            *(uint4*)(out_hi + base + 4) = make_uint4(hi_a[4], hi_a[5], hi_a[6], hi_a[7]);
        }
    } else {
        for (int e = 0; e < 8; e++) {
            int i = base + e;
            if (i < n) {
                u64 x = eb + texcl + pref[e];
                out_lo[i] = (u32)x;
                if (MODE == 0) out_hi[i] = (u32)(x >> 32);
            }
        }
    }
}

// ---------------- stage-1 scatter ----------------
__global__ void k_scatter(const u32* pvid, int n, const u32* starts, u32* cursor, u32* ptbuf)
{
    int i = blockIdx.x * blockDim.x + threadIdx.x;
    if (i >= n) return;
    u32 g = pvid[i];
    if (g == 0xFFFFFFFFu) return;
    u32 pos = atomicAdd(&cursor[g], 1u);
    ptbuf[starts[g] + pos] = (u32)i;
}

// ---------------- fused: per-cell sort + voxel build + roi mask ----------------
__global__ void k_cells(const u32* cnt1, const u32* starts, const u32* flagsc,
                        const u32* roibm, u32* ptbuf, u32* npm, u32* vstart)
{
    int c = blockIdx.x * blockDim.x + threadIdx.x;
    if (c >= NC1) return;
    u32 n = cnt1[c];
    if (!n) return;
    int f = c / C1, lv = c % C1;
    u32 slot = flagsc[c] - flagsc[f * C1];
    if (slot >= MAXV) return;
    int cx = lv % GX1, cy = lv / GX1;
    u32 idx = (u32)f * MAXV + slot;
    u32 s0 = starts[c];
    vstart[idx] = s0;
    u32 bit = (roibm[(size_t)f * (GY1 * RBW) + cy * RBW + (cx >> 5)] >> (cx & 31)) & 1u;
    if (!bit) return;  // npm stays 0 from init
    npm[idx] = n < 32u ? n : 32u;
    // stable order within voxel = ascending point index: insertion sort
    for (u32 a = 1; a < n; a++) {
        u32 v = ptbuf[s0 + a];
        int bp2 = (int)a;
        while (bp2 > 0 && ptbuf[s0 + bp2 - 1] > v) { ptbuf[s0 + bp2] = ptbuf[s0 + bp2 - 1]; bp2--; }
        ptbuf[s0 + bp2] = v;
    }
}

// ---------------- emit kept points, mark fine-voxel bitmap ----------------
__global__ void k_emitkept(const float* P, const u32* npm, const u32* koff, const u32* vstart,
                           const u32* ptbuf, u32* kept, u32* fvid, u32* bitmap)
{
    int idx = blockIdx.x * blockDim.x + threadIdx.x;
    if (idx >= NF * MAXV) return;
    u32 m = npm[idx];
    if (!m) return;
    u32 base = koff[idx];
    u32 vs = vstart[idx];
    u32 f = (u32)idx / MAXV;
    for (u32 r = 0; r < m; r++) {
        u32 pidx = ptbuf[vs + r];
        u32 seq = base + r;
        kept[seq] = pidx;
        const float* p = P + (size_t)pidx * 6;
        float fx = floorf((p[1] - PCX) / VSH);
        float fy = floorf((p[2] - PCY) / VSH);
        float fz = floorf((p[3] - PCZ) / VSH);
        u32 pk = 0xFFFFFFFFu;
        if (fx >= 0.f && fx < (float)GX2 && fy >= 0.f && fy < (float)GY2 &&
            fz >= 0.f && fz < (float)GZ2) {
            u32 vid = ((u32)fz * GY2 + (u32)fy) * GX2 + (u32)fx;
            pk = (f << 25) | vid;
            atomicOr(&bitmap[f * WPF + (vid >> 5)], 1u << (vid & 31));
        }
        fvid[seq] = pk;
    }
}

// ---------------- insert kept seqs into per-voxel 5-min sorted arrays ----------------
__global__ void k_insert(const u32* fvid, const u32* koffend, const u32* bitmap,
                         const u32* wordpref, u32* slotseq)
{
    u32 i = blockIdx.x * blockDim.x + threadIdx.x;
    u32 Mt = koffend[0];
    if (i >= Mt) return;
    u32 pk = fvid[i];
    if (pk == 0xFFFFFFFFu) return;
    u32 f = pk >> 25, vid = pk & 0x1FFFFFFu;
    u32 gw = f * WPF + (vid >> 5);
    u32 slot = wordpref[gw] - wordpref[f * WPF] +
               (u32)__popc(bitmap[gw] & ((1u << (vid & 31)) - 1u));
    if (slot >= (u32)MAXV) return;
    u32* arr = slotseq + (size_t)(f * MAXV + slot) * KK2;
    u32 val = i;
    #pragma unroll
    for (int j = 0; j < KK2; j++) {
        u32 old = atomicMin(&arr[j], val);
        if (old == 0xFFFFFFFFu) break;     // landed in empty slot
        val = old > val ? old : val;       // carry displaced value
    }
}

// ---------------- per-(frame, roi) selection + output ----------------
__global__ void __launch_bounds__(256) k_output(const float* P, const u32* boxp,
    const u32* bitmap, const u32* wordpref, const u32* slotseq, const u32* kept, float* out)
{
    __shared__ u32 rpref_s[MAXROWS];
    __shared__ u32 ssum[256];
    __shared__ int sidx[NSAMP];
    __shared__ float feat[KK2 * NSAMP][5];
    __shared__ u32 pmf[KK2 * NSAMP];
    __shared__ int sel[NSAMP];
    __shared__ int nsel_s;
    __shared__ u32 M_s;

    int bid = blockIdx.x, tid = threadIdx.x;
    int f = bid / RR, r = bid % RR;
    int b = f / TT, t = f % TT;
    const u32* bp = boxp + bid * 12;
    float bx = __uint_as_float(bp[0]);
    float by = __uint_as_float(bp[1]);
    float cr2 = __uint_as_float(bp[2]);
    float zmax = __uint_as_float(bp[3]);
    int Q1x = (int)bp[7], Q1y = (int)bp[8], irad2 = (int)bp[9];

    const u32* bmf = bitmap + (size_t)f * WPF;
    u32 wp_f0 = wordpref[f * WPF];
    u32 nv2u = wordpref[(f + 1) * WPF] - wp_f0;
    int nv2 = (nv2u > (u32)MAXV) ? MAXV : (int)nv2u;

    int cxlo = Q1x - irad2 + 1; if (cxlo < 0) cxlo = 0;
    int cxhi = Q1x + irad2 - 1; if (cxhi > GX2 - 1) cxhi = GX2 - 1;
    int cylo = Q1y - irad2 + 1; if (cylo < 0) cylo = 0;
    int cyhi = Q1y + irad2 - 1; if (cyhi > GY2 - 1) cyhi = GY2 - 1;
    int ny = cyhi - cylo + 1;
    int nrows = (cxlo <= cxhi && cylo <= cyhi) ? GZ2 * ny : 0;
    if (nrows > MAXROWS) nrows = MAXROWS;

    // phase A: per-row match counts via bitmap popcount (blocked per thread)
    u32 myrpref[RPT];
    u32 lsum = 0;
    #pragma unroll
    for (int e = 0; e < RPT; e++) {
        int ri = tid * RPT + e;
        myrpref[e] = lsum;
        if (ri < nrows) {
            int cz = ri / ny, cy = cylo + (ri - cz * ny);
            u32 vlo = ((u32)cz * GY2 + (u32)cy) * GX2 + (u32)cxlo;
            u32 vhi = vlo + (u32)(cxhi - cxlo);
            u32 gwlo = vlo >> 5, gwhi = vhi >> 5;
            u32 c = 0;
            for (u32 gw = gwlo; gw <= gwhi; gw++) {
                u32 w = bmf[gw];
                u32 lob = (gw == gwlo) ? (vlo & 31u) : 0u;
                u32 hib = (gw == gwhi) ? (vhi & 31u) : 31u;
                u32 m = (hib == 31u ? 0xFFFFFFFFu : ((1u << (hib + 1)) - 1u)) & ~((1u << lob) - 1u);
                c += (u32)__popc(w & m);
            }
            lsum += c;
        }
    }
    ssum[tid] = lsum;
    __syncthreads();
    for (int off = 1; off < 256; off <<= 1) {
        u32 y = (tid >= off) ? ssum[tid - off] : 0;
        __syncthreads();
        ssum[tid] += y;
        __syncthreads();
    }
    u32 texcl = ssum[tid] - lsum;
    if (tid == 255) M_s = ssum[255];
    #pragma unroll
    for (int e = 0; e < RPT; e++) {
        int ri = tid * RPT + e;
        if (ri < MAXROWS) rpref_s[ri] = texcl + myrpref[e];
    }
    __syncthreads();

    u32 M = M_s;
    int nt = (int)(M < (u32)NSAMP ? M : (u32)NSAMP);
    // phase B1: tid-th matched voxel in ascending vid order -> slot via wordpref rank
    if (tid < nt) {
        int lo = 0, hi = nrows - 1;
        while (lo < hi) { int m = (lo + hi + 1) >> 1; if (rpref_s[m] <= (u32)tid) lo = m; else hi = m - 1; }
        u32 rem = (u32)tid - rpref_s[lo];
        int cz = lo / ny, cy = cylo + (lo - cz * ny);
        u32 vlo = ((u32)cz * GY2 + (u32)cy) * GX2 + (u32)cxlo;
        u32 vhi = vlo + (u32)(cxhi - cxlo);
        u32 gwlo = vlo >> 5, gwhi = vhi >> 5;
        int slot = 0;
        for (u32 gw = gwlo; gw <= gwhi; gw++) {
            u32 w = bmf[gw];
            u32 lob = (gw == gwlo) ? (vlo & 31u) : 0u;
            u32 hib = (gw == gwhi) ? (vhi & 31u) : 31u;
            u32 m = (hib == 31u ? 0xFFFFFFFFu : ((1u << (hib + 1)) - 1u)) & ~((1u << lob) - 1u);
            u32 wm = w & m;
            u32 pc = (u32)__popc(wm);
            if (rem < pc) {
                for (u32 k = 0; k < rem; k++) wm &= wm - 1u;
                u32 bit = (u32)__ffs(wm) - 1u;
                slot = (int)(wordpref[f * WPF + gw] - wp_f0 + (u32)__popc(w & ((1u << bit) - 1u)));
                break;
            }
            rem -= pc;
        }
        sidx[tid] = slot;
    }
    __syncthreads();
    // phase B2: top_k false-fill with lowest non-matching slot indices
    if (tid == 0) {
        int c = nt, p = 0, s = 0;
        while (c < NSAMP) {
            if (p < nt && sidx[p] == s) { p++; s++; continue; }
            sidx[c++] = s++;
        }
    }
    __syncthreads();

    // phase C: gather sv in flat (k2-major) order, evaluate pm
    for (int j = tid; j < KK2 * NSAMP; j += 256) {
        int k2 = j >> 5, s = j & 31;
        int slot = sidx[s];
        float px = 0.f, py = 0.f, pz = 0.f, pi = 0.f, pt = 0.f;
        if (slot < nv2) {
            u32 seq = slotseq[(size_t)(f * MAXV + slot) * KK2 + k2];
            if (seq != 0xFFFFFFFFu) {
                u32 pidx = kept[seq];
                const float* p = P + (size_t)pidx * 6;
                px = p[1]; py = p[2]; pz = p[3]; pi = p[4]; pt = p[5];
            }
        }
        feat[j][0] = px; feat[j][1] = py; feat[j][2] = pz; feat[j][3] = pi; feat[j][4] = pt;
        float ex = px - bx, ey = py - by;
        pmf[j] = (ex * ex + ey * ey < cr2 && pz <= zmax) ? 1u : 0u;
    }
    __syncthreads();

    // phase D: top_k over pm in flat order
    if (tid == 0) {
        int c = 0;
        for (int j = 0; j < KK2 * NSAMP && c < NSAMP; j++)
            if (pmf[j]) sel[c++] = j;
        nsel_s = c;
    }
    __syncthreads();

    // phase E: write 32 rows x 5 feats
    int obase = ((b * RR + r) * (TT * NSAMP) + t * NSAMP) * 5;
    for (int w = tid; w < NSAMP * 5; w += 256) {
        int row = w / 5, col = w % 5;
        float v = (row < nsel_s) ? feat[sel[row]][col] : 0.f;
        out[obase + w] = v;
    }
}

extern "C" void kernel_launch(void* const* d_in, const int* in_sizes, int n_in,
                              void* d_out, int out_size, void* d_ws, size_t ws_size,
                              hipStream_t stream)
{
    const float* P = (const float*)d_in[0];
    const float* traj = (const float*)d_in[1];
    const float* back = (const float*)d_in[2];
    const unsigned char* vlb = (const unsigned char*)d_in[3];
    float* out = (float*)d_out;
    int N = in_sizes[0] / 6;
    if (N > NMAXP) N = NMAXP;

    char* cur = (char*)d_ws;
    auto carve = [&](size_t bytes) -> char* {
        char* p = cur;
        cur += (bytes + 255) & ~(size_t)255;
        return p;
    };

    // ---- zero zone 1: cnt1 + cursor ----
    char* zoneZ1 = cur;
    u32* cnt1   = (u32*)carve((size_t)NC1 * 4);
    u32* cursor = (u32*)carve((size_t)NC1 * 4);
    size_t z1_bytes = (size_t)(cur - zoneZ1);
    // ---- scan outputs (fully written by scans, no init) ----
    u32* flagsc = (u32*)carve((size_t)(NC1 + 1) * 4);
    u32* starts = (u32*)carve((size_t)(NC1 + 1) * 4);
    // wordpref aliases [cnt1, cursor, flagsc, starts] (18.1MB >= 17MB); those are dead before scan<3>
    u32* wordpref = (u32*)zoneZ1;
    // ---- zero zone 2: npm + roibm + bitmap + scan status + tickets ----
    char* zoneZ2 = cur;
    u32* npm     = (u32*)carve((size_t)NF * MAXV * 4);
    u32* roibm   = (u32*)carve((size_t)NF * GY1 * RBW * 4);
    u32* bitmap  = (u32*)carve((size_t)NF * WPF * 4);
    u64* status  = (u64*)carve((size_t)3 * STN * 8);
    u32* tickets = (u32*)carve(64);
    size_t z2_bytes = (size_t)(cur - zoneZ2);
    // ---- 0xFF zone: slotseq ----
    u32* slotseq = (u32*)carve((size_t)NF * MAXV * KK2 * 4);
    size_t ff_bytes = (size_t)(cur - (char*)slotseq);

    u32* pvid   = (u32*)carve((size_t)NMAXP * 4);
    u32* ptbuf  = (u32*)carve((size_t)NMAXP * 4);
    u32* vstart = (u32*)carve((size_t)NF * MAXV * 4);
    u32* koff   = (u32*)carve((size_t)(NF * MAXV + 1) * 4);
    u32* boxp   = (u32*)carve((size_t)NF * RR * 12 * 4);
    u32* kept   = (u32*)carve((size_t)NMAXP * 4);
    u32* fvid   = (u32*)carve((size_t)NMAXP * 4);
    if ((size_t)(cur - (char*)d_ws) > ws_size) return;  // insufficient workspace

    k_init<<<1024, 256, 0, stream>>>((u32*)zoneZ1, (u32)(z1_bytes / 16),
                                     (u32*)zoneZ2, (u32)(z2_bytes / 16),
                                     slotseq, (u32)(ff_bytes / 16));

    k_roipts<<<(N + 255) / 256, 256, 0, stream>>>(P, N, traj, back, vlb, boxp, roibm, pvid, cnt1);

    {   // scan 0: cnt1 -> starts (count prefix) + flagsc (occupancy prefix)
        int n = NC1, nt = (n + 2047) / 2048;
        k_scan_lb<0><<<nt, 256, 0, stream>>>(cnt1, starts, flagsc, status, &tickets[0], n, nt);
    }

    k_scatter<<<(N + 255) / 256, 256, 0, stream>>>(pvid, N, starts, cursor, ptbuf);
    k_cells<<<(NC1 + 255) / 256, 256, 0, stream>>>(cnt1, starts, flagsc, roibm, ptbuf, npm, vstart);

    {   // scan 1: npm -> koff
        int n = NF * MAXV, nt = (n + 2047) / 2048;
        k_scan_lb<1><<<nt, 256, 0, stream>>>(npm, koff, nullptr, status + STN, &tickets[1], n, nt);
    }

    k_emitkept<<<(NF * MAXV + 255) / 256, 256, 0, stream>>>(P, npm, koff, vstart, ptbuf, kept, fvid, bitmap);

    {   // scan 3: bitmap -> wordpref (popcount prefix)
        int n = NF * WPF, nt = (n + 2047) / 2048;
        k_scan_lb<3><<<nt, 256, 0, stream>>>(bitmap, wordpref, nullptr, status + 2 * STN, &tickets[2], n, nt);
    }

    k_insert<<<NPAD / 256, 256, 0, stream>>>(fvid, koff + NF * MAXV, bitmap, wordpref, slotseq);
    k_output<<<NF * RR, 256, 0, stream>>>(P, boxp, bitmap, wordpref, slotseq, kept, out);
}

// Round 5
// 159.833 us; speedup vs baseline: 7.5923x; 7.5923x over previous
//
#include <hip/hip_runtime.h>

typedef unsigned int u32;
typedef unsigned long long u64;

#define BB 2
#define TT 4
#define NF 8            // B*T frames
#define RR 128          // rois
#define NSAMP 32        // num_sample
#define KK2 5           // max points per fine voxel
#define MAXV 50000
#define GX1 376
#define GY1 376
#define C1 141376       // GX1*GY1 (gz=1)
#define NC1 1131008     // NF*C1
#define GX2 752
#define GY2 752
#define GZ2 30
#define WPF 530160      // bitmap words per frame = GX2*GY2*GZ2/32
#define RBW 12          // roibm words per row (376 bits)
#define NPAD 262144
#define NMAXP 262144
#define MAXROWS 1536
#define RPT 6           // rows per thread in k_output (256*6 = 1536)
#define STN 2112        // status entries per scan (>= max tiles 2071)

#define PCX (-75.2f)
#define PCY (-75.2f)
#define PCZ (-2.0f)
#define VS1 0.4f
#define VSH 0.2f
#define VZ1 6.0f

// ---------------- workspace init ----------------
// z0,z1: zero segments; f2: 0xFF segment. Counts are in uint4 units.
__global__ void k_init(u32* z0, u32 n0, u32* z1, u32 n1, u32* f2, u32 n2)
{
    u32 tid = blockIdx.x * blockDim.x + threadIdx.x;
    u32 stride = gridDim.x * blockDim.x;
    uint4 zz = make_uint4(0u, 0u, 0u, 0u);
    uint4 fv = make_uint4(~0u, ~0u, ~0u, ~0u);
    for (u32 i = tid; i < n0; i += stride) ((uint4*)z0)[i] = zz;
    for (u32 i = tid; i < n1; i += stride) ((uint4*)z1)[i] = zz;
    for (u32 i = tid; i < n2; i += stride) ((uint4*)f2)[i] = fv;
}

// ---------------- fused: box params + roi raster + stage-1 point voxelize ----------------
// boxp layout per (f,r), 12 u32 words:
// 0:bx 1:by 2:cur_r^2 3:zmax (floats); 4:Qx 5:Qy 6:irad 7:Q1x 8:Q1y 9:irad2 (ints)
__global__ void k_roipts(const float* P, int n, const float* traj, const float* back,
                         const unsigned char* vlb, u32* boxp, u32* roibm, u32* pvid, u32* cnt1)
{
    int i = blockIdx.x * blockDim.x + threadIdx.x;
    if (i < NF * RR) {
        // detect valid_length storage: int32 (0/1 -> bytes at %4!=0 are 0) vs uint8/bool
        bool isU8 = false;
        for (int k = 1; k < 64; k++)
            if ((k & 3) && vlb[k]) isU8 = true;
        bool vl = isU8 ? (vlb[i] != 0) : (((const int*)vlb)[i] != 0);
        const float* tb = traj + i * 7;
        const float* bb = back + i * 7;
        float bx = vl ? (tb[0] + bb[0]) * 0.5f : bb[0];
        float by = vl ? (tb[1] + bb[1]) * 0.5f : bb[1];
        float bz = bb[2], dx = bb[3], dy = bb[4], dz = bb[5];
        float hx = dx * 0.5f, hy = dy * 0.5f;
        float r0 = sqrtf(hx * hx + hy * hy);
        float radf = ceilf(r0 * 1.1f / 0.4f);
        float curr = r0 * 1.1f;
        u32* bp = boxp + i * 12;
        int Qx = (int)floorf((bx - PCX) / VS1);
        int Qy = (int)floorf((by - PCY) / VS1);
        int ir = (int)radf;
        bp[0] = __float_as_uint(bx);
        bp[1] = __float_as_uint(by);
        bp[2] = __float_as_uint(curr * curr);
        bp[3] = __float_as_uint(bz + dz * 0.6f);
        bp[4] = (u32)Qx;
        bp[5] = (u32)Qy;
        bp[6] = (u32)ir;
        bp[7] = (u32)(int)floorf((bx - PCX) / VSH);
        bp[8] = (u32)(int)floorf((by - PCY) / VSH);
        bp[9] = (u32)(2 * ir);

        int f = i / RR;
        int xlo = Qx - ir + 1; if (xlo < 0) xlo = 0;
        int xhi = Qx + ir - 1; if (xhi > GX1 - 1) xhi = GX1 - 1;
        int ylo = Qy - ir + 1; if (ylo < 0) ylo = 0;
        int yhi = Qy + ir - 1; if (yhi > GY1 - 1) yhi = GY1 - 1;
        if (xlo <= xhi && ylo <= yhi) {
            int w0 = xlo >> 5, w1 = xhi >> 5;
            for (int cy = ylo; cy <= yhi; cy++) {
                u32* row = roibm + (size_t)f * (GY1 * RBW) + cy * RBW;
                for (int w = w0; w <= w1; w++) {
                    int lo = xlo - (w << 5); if (lo < 0) lo = 0;
                    int hi = xhi - (w << 5); if (hi > 31) hi = 31;
                    u32 m = (hi == 31 ? 0xFFFFFFFFu : ((1u << (hi + 1)) - 1u)) & ~((1u << lo) - 1u);
                    atomicOr(&row[w], m);
                }
            }
        }
    }
    if (i < n) {
        const float* p = P + (size_t)i * 6;
        float bsf = p[0], x = p[1], y = p[2], z = p[3], tt = p[5];
        u32 g = 0xFFFFFFFFu;
        int b = (int)bsf;
        int t = (int)floorf(tt * 10.0f + 0.5f);
        if (bsf == (float)b && b >= 0 && b < BB && t >= 0 && t < TT &&
            fabsf(tt - 0.1f * (float)t) < 0.001f) {
            float fx = floorf((x - PCX) / VS1);
            float fy = floorf((y - PCY) / VS1);
            float fz = floorf((z - PCZ) / VZ1);
            if (fx >= 0.f && fx < (float)GX1 && fy >= 0.f && fy < (float)GY1 && fz == 0.f) {
                g = (u32)((b * TT + t) * C1) + (u32)fy * GX1 + (u32)fx;
            }
        }
        pvid[i] = g;
        if (g != 0xFFFFFFFFu) atomicAdd(&cnt1[g], 1u);
    }
}

// ---------------- single-pass decoupled-lookback exclusive scan ----------------
// MODE 0: in=counts -> lo:prefix(count) hi:prefix(count!=0)
// MODE 1: in=u32    -> lo:prefix(in)
// MODE 3: in=bitmap -> lo:prefix(popcount)
// status word (self-contained, single u64 => RELAXED atomics suffice):
//   state(2b)<<62 | hi(28b)<<28 | lo(28b); all running sums < 2^28.
// Ticket-ordered tile assignment guarantees forward progress.
// Lookback is WAVE-PARALLEL: wave 3's 64 lanes poll 64 predecessors per round.
template <int MODE>
__global__ void __launch_bounds__(256) k_scan_lb(const u32* in, u32* out_lo, u32* out_hi,
                                                 u64* status, u32* ticket, int n, int ntiles)
{
    __shared__ u64 sh[256];
    __shared__ u64 excl_sh;
    __shared__ u32 vt_sh;
    int t = threadIdx.x;
    if (t == 0) vt_sh = atomicAdd(ticket, 1u);
    __syncthreads();
    int vt = (int)vt_sh;
    int base = vt * 2048 + t * 8;
    u32 v[8];
    if (base + 8 <= n) {
        uint4 a = *(const uint4*)(in + base);
        uint4 bq = *(const uint4*)(in + base + 4);
        v[0] = a.x; v[1] = a.y; v[2] = a.z; v[3] = a.w;
        v[4] = bq.x; v[5] = bq.y; v[6] = bq.z; v[7] = bq.w;
    } else {
        #pragma unroll
        for (int e = 0; e < 8; e++) { int i = base + e; v[e] = (i < n) ? in[i] : 0u; }
    }
    u64 pref[8]; u64 sum = 0;
    #pragma unroll
    for (int e = 0; e < 8; e++) {
        u64 val;
        if (MODE == 0)      val = (u64)v[e] | ((u64)(v[e] != 0u) << 32);
        else if (MODE == 1) val = v[e];
        else                val = (u32)__popc(v[e]);
        pref[e] = sum; sum += val;
    }
    sh[t] = sum;
    __syncthreads();
    for (int off = 1; off < 256; off <<= 1) {
        u64 y = (t >= off) ? sh[t - off] : 0;
        __syncthreads();
        sh[t] += y;
        __syncthreads();
    }
    u64 texcl = sh[t] - sum;
    u64 total = sh[255];
    u32 tlo = (u32)(total & 0xFFFFFFFFull), thi = (u32)(total >> 32);

    if (vt == 0) {
        if (t == 0) {
            __hip_atomic_store(&status[0], (2ull << 62) | ((u64)thi << 28) | (u64)tlo,
                               __ATOMIC_RELAXED, __HIP_MEMORY_SCOPE_AGENT);
            excl_sh = 0;
            if (ntiles == 1) { out_lo[n] = tlo; if (MODE == 0) out_hi[n] = thi; }
        }
    } else {
        if (t == 255)
            __hip_atomic_store(&status[vt], (1ull << 62) | ((u64)thi << 28) | (u64)tlo,
                               __ATOMIC_RELAXED, __HIP_MEMORY_SCOPE_AGENT);
        if (t >= 192) {          // wave 3: lane-parallel lookback
            int lane = t - 192;
            u32 elo = 0, ehi = 0;
            int bidx = vt - 1;
            while (true) {
                int idx = bidx - lane;
                u64 s;
                if (idx >= 0) {
                    do {
                        s = __hip_atomic_load(&status[idx], __ATOMIC_RELAXED,
                                              __HIP_MEMORY_SCOPE_AGENT);
                    } while ((s >> 62) == 0ull);
                } else {
                    s = 2ull << 62;   // virtual inclusive-0 before the beginning
                }
                u64 bal = __ballot((s >> 62) == 2ull);
                u32 clo, chi;
                if (bal) {
                    u32 L = (u32)__ffsll((unsigned long long)bal) - 1u;  // nearest state-2
                    clo = ((u32)lane <= L) ? (u32)(s & 0xFFFFFFFull) : 0u;
                    chi = ((u32)lane <= L) ? (u32)((s >> 28) & 0xFFFFFFFull) : 0u;
                } else {
                    clo = (u32)(s & 0xFFFFFFFull);
                    chi = (u32)((s >> 28) & 0xFFFFFFFull);
                }
                #pragma unroll
                for (int off = 1; off < 64; off <<= 1) {
                    clo += __shfl_xor(clo, off, 64);
                    chi += __shfl_xor(chi, off, 64);
                }
                elo += clo; ehi += chi;
                if (bal) break;
                bidx -= 64;
            }
            if (lane == 0) {
                __hip_atomic_store(&status[vt],
                    (2ull << 62) | ((u64)(thi + ehi) << 28) | (u64)(tlo + elo),
                    __ATOMIC_RELAXED, __HIP_MEMORY_SCOPE_AGENT);
                excl_sh = (u64)elo | ((u64)ehi << 32);
                if (vt == ntiles - 1) {
                    out_lo[n] = tlo + elo;
                    if (MODE == 0) out_hi[n] = thi + ehi;
                }
            }
        }
    }
    __syncthreads();
    u64 eb = excl_sh;
    if (base + 8 <= n) {
        u32 lo_a[8], hi_a[8];
        #pragma unroll
        for (int e = 0; e < 8; e++) {
            u64 x = eb + texcl + pref[e];
            lo_a[e] = (u32)x; hi_a[e] = (u32)(x >> 32);
        }
        *(uint4*)(out_lo + base)     = make_uint4(lo_a[0], lo_a[1], lo_a[2], lo_a[3]);
        *(uint4*)(out_lo + base + 4) = make_uint4(lo_a[4], lo_a[5], lo_a[6], lo_a[7]);
        if (MODE == 0) {
            *(uint4*)(out_hi + base)     = make_uint4(hi_a[0], hi_a[1], hi_a[2], hi_a[3]);
            *(uint4*)(out_hi + base + 4) = make_uint4(hi_a[4], hi_a[5], hi_a[6], hi_a[7]);
        }
    } else {
        for (int e = 0; e < 8; e++) {
            int i = base + e;
            if (i < n) {
                u64 x = eb + texcl + pref[e];
                out_lo[i] = (u32)x;
                if (MODE == 0) out_hi[i] = (u32)(x >> 32);
            }
        }
    }
}

// ---------------- stage-1 scatter ----------------
__global__ void k_scatter(const u32* pvid, int n, const u32* starts, u32* cursor, u32* ptbuf)
{
    int i = blockIdx.x * blockDim.x + threadIdx.x;
    if (i >= n) return;
    u32 g = pvid[i];
    if (g == 0xFFFFFFFFu) return;
    u32 pos = atomicAdd(&cursor[g], 1u);
    ptbuf[starts[g] + pos] = (u32)i;
}

// ---------------- fused: per-cell sort + voxel build + roi mask ----------------
__global__ void k_cells(const u32* cnt1, const u32* starts, const u32* flagsc,
                        const u32* roibm, u32* ptbuf, u32* npm, u32* vstart)
{
    int c = blockIdx.x * blockDim.x + threadIdx.x;
    if (c >= NC1) return;
    u32 n = cnt1[c];
    if (!n) return;
    int f = c / C1, lv = c % C1;
    u32 slot = flagsc[c] - flagsc[f * C1];
    if (slot >= MAXV) return;
    int cx = lv % GX1, cy = lv / GX1;
    u32 idx = (u32)f * MAXV + slot;
    u32 s0 = starts[c];
    vstart[idx] = s0;
    u32 bit = (roibm[(size_t)f * (GY1 * RBW) + cy * RBW + (cx >> 5)] >> (cx & 31)) & 1u;
    if (!bit) return;  // npm stays 0 from init
    npm[idx] = n < 32u ? n : 32u;
    // stable order within voxel = ascending point index: insertion sort
    for (u32 a = 1; a < n; a++) {
        u32 v = ptbuf[s0 + a];
        int bp2 = (int)a;
        while (bp2 > 0 && ptbuf[s0 + bp2 - 1] > v) { ptbuf[s0 + bp2] = ptbuf[s0 + bp2 - 1]; bp2--; }
        ptbuf[s0 + bp2] = v;
    }
}

// ---------------- emit kept points, mark fine-voxel bitmap ----------------
__global__ void k_emitkept(const float* P, const u32* npm, const u32* koff, const u32* vstart,
                           const u32* ptbuf, u32* kept, u32* fvid, u32* bitmap)
{
    int idx = blockIdx.x * blockDim.x + threadIdx.x;
    if (idx >= NF * MAXV) return;
    u32 m = npm[idx];
    if (!m) return;
    u32 base = koff[idx];
    u32 vs = vstart[idx];
    u32 f = (u32)idx / MAXV;
    for (u32 r = 0; r < m; r++) {
        u32 pidx = ptbuf[vs + r];
        u32 seq = base + r;
        kept[seq] = pidx;
        const float* p = P + (size_t)pidx * 6;
        float fx = floorf((p[1] - PCX) / VSH);
        float fy = floorf((p[2] - PCY) / VSH);
        float fz = floorf((p[3] - PCZ) / VSH);
        u32 pk = 0xFFFFFFFFu;
        if (fx >= 0.f && fx < (float)GX2 && fy >= 0.f && fy < (float)GY2 &&
            fz >= 0.f && fz < (float)GZ2) {
            u32 vid = ((u32)fz * GY2 + (u32)fy) * GX2 + (u32)fx;
            pk = (f << 25) | vid;
            atomicOr(&bitmap[f * WPF + (vid >> 5)], 1u << (vid & 31));
        }
        fvid[seq] = pk;
    }
}

// ---------------- insert kept seqs into per-voxel 5-min sorted arrays ----------------
__global__ void k_insert(const u32* fvid, const u32* koffend, const u32* bitmap,
                         const u32* wordpref, u32* slotseq)
{
    u32 i = blockIdx.x * blockDim.x + threadIdx.x;
    u32 Mt = koffend[0];
    if (i >= Mt) return;
    u32 pk = fvid[i];
    if (pk == 0xFFFFFFFFu) return;
    u32 f = pk >> 25, vid = pk & 0x1FFFFFFu;
    u32 gw = f * WPF + (vid >> 5);
    u32 slot = wordpref[gw] - wordpref[f * WPF] +
               (u32)__popc(bitmap[gw] & ((1u << (vid & 31)) - 1u));
    if (slot >= (u32)MAXV) return;
    u32* arr = slotseq + (size_t)(f * MAXV + slot) * KK2;
    u32 val = i;
    #pragma unroll
    for (int j = 0; j < KK2; j++) {
        u32 old = atomicMin(&arr[j], val);
        if (old == 0xFFFFFFFFu) break;     // landed in empty slot
        val = old > val ? old : val;       // carry displaced value
    }
}

// ---------------- per-(frame, roi) selection + output ----------------
__global__ void __launch_bounds__(256) k_output(const float* P, const u32* boxp,
    const u32* bitmap, const u32* wordpref, const u32* slotseq, const u32* kept, float* out)
{
    __shared__ u32 rpref_s[MAXROWS];
    __shared__ u32 ssum[256];
    __shared__ int sidx[NSAMP];
    __shared__ float feat[KK2 * NSAMP][5];
    __shared__ u32 pmf[KK2 * NSAMP];
    __shared__ int sel[NSAMP];
    __shared__ int nsel_s;
    __shared__ u32 M_s;

    int bid = blockIdx.x, tid = threadIdx.x;
    int f = bid / RR, r = bid % RR;
    int b = f / TT, t = f % TT;
    const u32* bp = boxp + bid * 12;
    float bx = __uint_as_float(bp[0]);
    float by = __uint_as_float(bp[1]);
    float cr2 = __uint_as_float(bp[2]);
    float zmax = __uint_as_float(bp[3]);
    int Q1x = (int)bp[7], Q1y = (int)bp[8], irad2 = (int)bp[9];

    const u32* bmf = bitmap + (size_t)f * WPF;
    u32 wp_f0 = wordpref[f * WPF];
    u32 nv2u = wordpref[(f + 1) * WPF] - wp_f0;
    int nv2 = (nv2u > (u32)MAXV) ? MAXV : (int)nv2u;

    int cxlo = Q1x - irad2 + 1; if (cxlo < 0) cxlo = 0;
    int cxhi = Q1x + irad2 - 1; if (cxhi > GX2 - 1) cxhi = GX2 - 1;
    int cylo = Q1y - irad2 + 1; if (cylo < 0) cylo = 0;
    int cyhi = Q1y + irad2 - 1; if (cyhi > GY2 - 1) cyhi = GY2 - 1;
    int ny = cyhi - cylo + 1;
    int nrows = (cxlo <= cxhi && cylo <= cyhi) ? GZ2 * ny : 0;
    if (nrows > MAXROWS) nrows = MAXROWS;

    // phase A: per-row match counts via bitmap popcount (blocked per thread)
    u32 myrpref[RPT];
    u32 lsum = 0;
    #pragma unroll
    for (int e = 0; e < RPT; e++) {
        int ri = tid * RPT + e;
        myrpref[e] = lsum;
        if (ri < nrows) {
            int cz = ri / ny, cy = cylo + (ri - cz * ny);
            u32 vlo = ((u32)cz * GY2 + (u32)cy) * GX2 + (u32)cxlo;
            u32 vhi = vlo + (u32)(cxhi - cxlo);
            u32 gwlo = vlo >> 5, gwhi = vhi >> 5;
            u32 c = 0;
            for (u32 gw = gwlo; gw <= gwhi; gw++) {
                u32 w = bmf[gw];
                u32 lob = (gw == gwlo) ? (vlo & 31u) : 0u;
                u32 hib = (gw == gwhi) ? (vhi & 31u) : 31u;
                u32 m = (hib == 31u ? 0xFFFFFFFFu : ((1u << (hib + 1)) - 1u)) & ~((1u << lob) - 1u);
                c += (u32)__popc(w & m);
            }
            lsum += c;
        }
    }
    ssum[tid] = lsum;
    __syncthreads();
    for (int off = 1; off < 256; off <<= 1) {
        u32 y = (tid >= off) ? ssum[tid - off] : 0;
        __syncthreads();
        ssum[tid] += y;
        __syncthreads();
    }
    u32 texcl = ssum[tid] - lsum;
    if (tid == 255) M_s = ssum[255];
    #pragma unroll
    for (int e = 0; e < RPT; e++) {
        int ri = tid * RPT + e;
        if (ri < MAXROWS) rpref_s[ri] = texcl + myrpref[e];
    }
    __syncthreads();

    u32 M = M_s;
    int nt = (int)(M < (u32)NSAMP ? M : (u32)NSAMP);
    // phase B1: tid-th matched voxel in ascending vid order -> slot via wordpref rank
    if (tid < nt) {
        int lo = 0, hi = nrows - 1;
        while (lo < hi) { int m = (lo + hi + 1) >> 1; if (rpref_s[m] <= (u32)tid) lo = m; else hi = m - 1; }
        u32 rem = (u32)tid - rpref_s[lo];
        int cz = lo / ny, cy = cylo + (lo - cz * ny);
        u32 vlo = ((u32)cz * GY2 + (u32)cy) * GX2 + (u32)cxlo;
        u32 vhi = vlo + (u32)(cxhi - cxlo);
        u32 gwlo = vlo >> 5, gwhi = vhi >> 5;
        int slot = 0;
        for (u32 gw = gwlo; gw <= gwhi; gw++) {
            u32 w = bmf[gw];
            u32 lob = (gw == gwlo) ? (vlo & 31u) : 0u;
            u32 hib = (gw == gwhi) ? (vhi & 31u) : 31u;
            u32 m = (hib == 31u ? 0xFFFFFFFFu : ((1u << (hib + 1)) - 1u)) & ~((1u << lob) - 1u);
            u32 wm = w & m;
            u32 pc = (u32)__popc(wm);
            if (rem < pc) {
                for (u32 k = 0; k < rem; k++) wm &= wm - 1u;
                u32 bit = (u32)__ffs(wm) - 1u;
                slot = (int)(wordpref[f * WPF + gw] - wp_f0 + (u32)__popc(w & ((1u << bit) - 1u)));
                break;
            }
            rem -= pc;
        }
        sidx[tid] = slot;
    }
    __syncthreads();
    // phase B2: top_k false-fill with lowest non-matching slot indices
    if (tid == 0) {
        int c = nt, p = 0, s = 0;
        while (c < NSAMP) {
            if (p < nt && sidx[p] == s) { p++; s++; continue; }
            sidx[c++] = s++;
        }
    }
    __syncthreads();

    // phase C: gather sv in flat (k2-major) order, evaluate pm
    for (int j = tid; j < KK2 * NSAMP; j += 256) {
        int k2 = j >> 5, s = j & 31;
        int slot = sidx[s];
        float px = 0.f, py = 0.f, pz = 0.f, pi = 0.f, pt = 0.f;
        if (slot < nv2) {
            u32 seq = slotseq[(size_t)(f * MAXV + slot) * KK2 + k2];
            if (seq != 0xFFFFFFFFu) {
                u32 pidx = kept[seq];
                const float* p = P + (size_t)pidx * 6;
                px = p[1]; py = p[2]; pz = p[3]; pi = p[4]; pt = p[5];
            }
        }
        feat[j][0] = px; feat[j][1] = py; feat[j][2] = pz; feat[j][3] = pi; feat[j][4] = pt;
        float ex = px - bx, ey = py - by;
        pmf[j] = (ex * ex + ey * ey < cr2 && pz <= zmax) ? 1u : 0u;
    }
    __syncthreads();

    // phase D: top_k over pm in flat order
    if (tid == 0) {
        int c = 0;
        for (int j = 0; j < KK2 * NSAMP && c < NSAMP; j++)
            if (pmf[j]) sel[c++] = j;
        nsel_s = c;
    }
    __syncthreads();

    // phase E: write 32 rows x 5 feats
    int obase = ((b * RR + r) * (TT * NSAMP) + t * NSAMP) * 5;
    for (int w = tid; w < NSAMP * 5; w += 256) {
        int row = w / 5, col = w % 5;
        float v = (row < nsel_s) ? feat[sel[row]][col] : 0.f;
        out[obase + w] = v;
    }
}

extern "C" void kernel_launch(void* const* d_in, const int* in_sizes, int n_in,
                              void* d_out, int out_size, void* d_ws, size_t ws_size,
                              hipStream_t stream)
{
    const float* P = (const float*)d_in[0];
    const float* traj = (const float*)d_in[1];
    const float* back = (const float*)d_in[2];
    const unsigned char* vlb = (const unsigned char*)d_in[3];
    float* out = (float*)d_out;
    int N = in_sizes[0] / 6;
    if (N > NMAXP) N = NMAXP;

    char* cur = (char*)d_ws;
    auto carve = [&](size_t bytes) -> char* {
        char* p = cur;
        cur += (bytes + 255) & ~(size_t)255;
        return p;
    };

    // ---- zero zone 1: cnt1 + cursor ----
    char* zoneZ1 = cur;
    u32* cnt1   = (u32*)carve((size_t)NC1 * 4);
    u32* cursor = (u32*)carve((size_t)NC1 * 4);
    size_t z1_bytes = (size_t)(cur - zoneZ1);
    // ---- scan outputs (fully written by scans, no init) ----
    u32* flagsc = (u32*)carve((size_t)(NC1 + 1) * 4);
    u32* starts = (u32*)carve((size_t)(NC1 + 1) * 4);
    // wordpref aliases [cnt1, cursor, flagsc, starts] (18.1MB >= 17MB); those are dead before scan<3>
    u32* wordpref = (u32*)zoneZ1;
    // ---- zero zone 2: npm + roibm + bitmap + scan status + tickets ----
    char* zoneZ2 = cur;
    u32* npm     = (u32*)carve((size_t)NF * MAXV * 4);
    u32* roibm   = (u32*)carve((size_t)NF * GY1 * RBW * 4);
    u32* bitmap  = (u32*)carve((size_t)NF * WPF * 4);
    u64* status  = (u64*)carve((size_t)3 * STN * 8);
    u32* tickets = (u32*)carve(64);
    size_t z2_bytes = (size_t)(cur - zoneZ2);
    // ---- 0xFF zone: slotseq ----
    u32* slotseq = (u32*)carve((size_t)NF * MAXV * KK2 * 4);
    size_t ff_bytes = (size_t)(cur - (char*)slotseq);

    u32* pvid   = (u32*)carve((size_t)NMAXP * 4);
    u32* ptbuf  = (u32*)carve((size_t)NMAXP * 4);
    u32* vstart = (u32*)carve((size_t)NF * MAXV * 4);
    u32* koff   = (u32*)carve((size_t)(NF * MAXV + 1) * 4);
    u32* boxp   = (u32*)carve((size_t)NF * RR * 12 * 4);
    u32* kept   = (u32*)carve((size_t)NMAXP * 4);
    u32* fvid   = (u32*)carve((size_t)NMAXP * 4);
    if ((size_t)(cur - (char*)d_ws) > ws_size) return;  // insufficient workspace

    k_init<<<1024, 256, 0, stream>>>((u32*)zoneZ1, (u32)(z1_bytes / 16),
                                     (u32*)zoneZ2, (u32)(z2_bytes / 16),
                                     slotseq, (u32)(ff_bytes / 16));

    k_roipts<<<(N + 255) / 256, 256, 0, stream>>>(P, N, traj, back, vlb, boxp, roibm, pvid, cnt1);

    {   // scan 0: cnt1 -> starts (count prefix) + flagsc (occupancy prefix)
        int n = NC1, nt = (n + 2047) / 2048;
        k_scan_lb<0><<<nt, 256, 0, stream>>>(cnt1, starts, flagsc, status, &tickets[0], n, nt);
    }

    k_scatter<<<(N + 255) / 256, 256, 0, stream>>>(pvid, N, starts, cursor, ptbuf);
    k_cells<<<(NC1 + 255) / 256, 256, 0, stream>>>(cnt1, starts, flagsc, roibm, ptbuf, npm, vstart);

    {   // scan 1: npm -> koff
        int n = NF * MAXV, nt = (n + 2047) / 2048;
        k_scan_lb<1><<<nt, 256, 0, stream>>>(npm, koff, nullptr, status + STN, &tickets[1], n, nt);
    }

    k_emitkept<<<(NF * MAXV + 255) / 256, 256, 0, stream>>>(P, npm, koff, vstart, ptbuf, kept, fvid, bitmap);

    {   // scan 3: bitmap -> wordpref (popcount prefix)
        int n = NF * WPF, nt = (n + 2047) / 2048;
        k_scan_lb<3><<<nt, 256, 0, stream>>>(bitmap, wordpref, nullptr, status + 2 * STN, &tickets[2], n, nt);
    }

    k_insert<<<NPAD / 256, 256, 0, stream>>>(fvid, koff + NF * MAXV, bitmap, wordpref, slotseq);
    k_output<<<NF * RR, 256, 0, stream>>>(P, boxp, bitmap, wordpref, slotseq, kept, out);
}

// Round 6
// 132.509 us; speedup vs baseline: 9.1579x; 1.2062x over previous
//
#include <hip/hip_runtime.h>

typedef unsigned int u32;
typedef unsigned long long u64;

#define BB 2
#define TT 4
#define NF 8            // B*T frames
#define RR 128          // rois
#define NSAMP 32        // num_sample
#define KK2 5           // max points per fine voxel
#define MAXV 50000
#define GX1 376
#define GY1 376
#define C1 141376       // GX1*GY1 (gz=1)
#define NC1 1131008     // NF*C1
#define GX2 752
#define GY2 752
#define GZ2 30
#define WPF 530160      // bitmap words per frame = GX2*GY2*GZ2/32
#define RBW 12          // roibm words per row (376 bits)
#define NPAD 262144
#define NMAXP 262144
#define MAXROWS 1536
#define RPT 6           // rows per thread in k_output (256*6 = 1536)
#define VPT 32          // scan words per thread
#define TILE 8192       // scan words per tile (256*VPT)
#define STN 576         // status entries per scan (>= max tiles 518)
#define SSTRIDE 16      // u64s between status entries (128B cache-line pad)

#define PCX (-75.2f)
#define PCY (-75.2f)
#define PCZ (-2.0f)
#define VS1 0.4f
#define VSH 0.2f
#define VZ1 6.0f

// ---------------- workspace init ----------------
// z0,z1: zero segments; f2: 0xFF segment. Counts are in uint4 units.
__global__ void k_init(u32* z0, u32 n0, u32* z1, u32 n1, u32* f2, u32 n2)
{
    u32 tid = blockIdx.x * blockDim.x + threadIdx.x;
    u32 stride = gridDim.x * blockDim.x;
    uint4 zz = make_uint4(0u, 0u, 0u, 0u);
    uint4 fv = make_uint4(~0u, ~0u, ~0u, ~0u);
    for (u32 i = tid; i < n0; i += stride) ((uint4*)z0)[i] = zz;
    for (u32 i = tid; i < n1; i += stride) ((uint4*)z1)[i] = zz;
    for (u32 i = tid; i < n2; i += stride) ((uint4*)f2)[i] = fv;
}

// ---------------- fused: box params + roi raster + stage-1 point voxelize ----------------
// boxp layout per (f,r), 12 u32 words:
// 0:bx 1:by 2:cur_r^2 3:zmax (floats); 4:Qx 5:Qy 6:irad 7:Q1x 8:Q1y 9:irad2 (ints)
__global__ void k_roipts(const float* P, int n, const float* traj, const float* back,
                         const unsigned char* vlb, u32* boxp, u32* roibm, u32* pvid, u32* cnt1)
{
    int i = blockIdx.x * blockDim.x + threadIdx.x;
    if (i < NF * RR) {
        // detect valid_length storage: int32 (0/1 -> bytes at %4!=0 are 0) vs uint8/bool
        bool isU8 = false;
        for (int k = 1; k < 64; k++)
            if ((k & 3) && vlb[k]) isU8 = true;
        bool vl = isU8 ? (vlb[i] != 0) : (((const int*)vlb)[i] != 0);
        const float* tb = traj + i * 7;
        const float* bb = back + i * 7;
        float bx = vl ? (tb[0] + bb[0]) * 0.5f : bb[0];
        float by = vl ? (tb[1] + bb[1]) * 0.5f : bb[1];
        float bz = bb[2], dx = bb[3], dy = bb[4], dz = bb[5];
        float hx = dx * 0.5f, hy = dy * 0.5f;
        float r0 = sqrtf(hx * hx + hy * hy);
        float radf = ceilf(r0 * 1.1f / 0.4f);
        float curr = r0 * 1.1f;
        u32* bp = boxp + i * 12;
        int Qx = (int)floorf((bx - PCX) / VS1);
        int Qy = (int)floorf((by - PCY) / VS1);
        int ir = (int)radf;
        bp[0] = __float_as_uint(bx);
        bp[1] = __float_as_uint(by);
        bp[2] = __float_as_uint(curr * curr);
        bp[3] = __float_as_uint(bz + dz * 0.6f);
        bp[4] = (u32)Qx;
        bp[5] = (u32)Qy;
        bp[6] = (u32)ir;
        bp[7] = (u32)(int)floorf((bx - PCX) / VSH);
        bp[8] = (u32)(int)floorf((by - PCY) / VSH);
        bp[9] = (u32)(2 * ir);

        int f = i / RR;
        int xlo = Qx - ir + 1; if (xlo < 0) xlo = 0;
        int xhi = Qx + ir - 1; if (xhi > GX1 - 1) xhi = GX1 - 1;
        int ylo = Qy - ir + 1; if (ylo < 0) ylo = 0;
        int yhi = Qy + ir - 1; if (yhi > GY1 - 1) yhi = GY1 - 1;
        if (xlo <= xhi && ylo <= yhi) {
            int w0 = xlo >> 5, w1 = xhi >> 5;
            for (int cy = ylo; cy <= yhi; cy++) {
                u32* row = roibm + (size_t)f * (GY1 * RBW) + cy * RBW;
                for (int w = w0; w <= w1; w++) {
                    int lo = xlo - (w << 5); if (lo < 0) lo = 0;
                    int hi = xhi - (w << 5); if (hi > 31) hi = 31;
                    u32 m = (hi == 31 ? 0xFFFFFFFFu : ((1u << (hi + 1)) - 1u)) & ~((1u << lo) - 1u);
                    atomicOr(&row[w], m);
                }
            }
        }
    }
    if (i < n) {
        const float* p = P + (size_t)i * 6;
        float bsf = p[0], x = p[1], y = p[2], z = p[3], tt = p[5];
        u32 g = 0xFFFFFFFFu;
        int b = (int)bsf;
        int t = (int)floorf(tt * 10.0f + 0.5f);
        if (bsf == (float)b && b >= 0 && b < BB && t >= 0 && t < TT &&
            fabsf(tt - 0.1f * (float)t) < 0.001f) {
            float fx = floorf((x - PCX) / VS1);
            float fy = floorf((y - PCY) / VS1);
            float fz = floorf((z - PCZ) / VZ1);
            if (fx >= 0.f && fx < (float)GX1 && fy >= 0.f && fy < (float)GY1 && fz == 0.f) {
                g = (u32)((b * TT + t) * C1) + (u32)fy * GX1 + (u32)fx;
            }
        }
        pvid[i] = g;
        if (g != 0xFFFFFFFFu) atomicAdd(&cnt1[g], 1u);
    }
}

// ---------------- single-pass decoupled-lookback exclusive scan ----------------
// MODE 0: in=counts -> lo:prefix(count) hi:prefix(count!=0)
// MODE 1: in=u32    -> lo:prefix(in)
// MODE 3: in=bitmap -> lo:prefix(popcount)
// status word (self-contained, single u64 => RELAXED atomics suffice):
//   state(2b)<<62 | hi(28b)<<28 | lo(28b); all running sums < 2^28.
// Entries padded to 128B (SSTRIDE) to avoid LLC line contention among pollers.
// Ticket-ordered tile assignment guarantees forward progress.
// Lookback is WAVE-PARALLEL: wave 3's 64 lanes poll 64 predecessors per round.
template <int MODE>
__global__ void __launch_bounds__(256) k_scan_lb(const u32* in, u32* out_lo, u32* out_hi,
                                                 u64* status, u32* ticket, int n, int ntiles)
{
    __shared__ u64 wsum_sh[4];
    __shared__ u64 excl_sh;
    __shared__ u32 vt_sh;
    int t = threadIdx.x;
    int lane = t & 63, wid = t >> 6;
    if (t == 0) vt_sh = atomicAdd(ticket, 1u);
    __syncthreads();
    int vt = (int)vt_sh;
    int base = vt * TILE + t * VPT;
    u32 v[VPT];
    bool full = (base + VPT <= n);
    if (full) {
        #pragma unroll
        for (int q = 0; q < VPT / 4; q++) {
            uint4 a = *(const uint4*)(in + base + q * 4);
            v[q * 4 + 0] = a.x; v[q * 4 + 1] = a.y; v[q * 4 + 2] = a.z; v[q * 4 + 3] = a.w;
        }
    } else {
        #pragma unroll
        for (int e = 0; e < VPT; e++) { int i = base + e; v[e] = (i < n) ? in[i] : 0u; }
    }
    auto val_of = [&](u32 x) -> u64 {
        if (MODE == 0)      return (u64)x | ((u64)(x != 0u) << 32);
        else if (MODE == 1) return (u64)x;
        else                return (u64)(u32)__popc(x);
    };
    u64 sum = 0;
    #pragma unroll
    for (int e = 0; e < VPT; e++) sum += val_of(v[e]);
    // wave-level inclusive scan (no barriers)
    u64 ws = sum;
    #pragma unroll
    for (int off = 1; off < 64; off <<= 1) {
        u64 y = __shfl_up(ws, off, 64);
        if (lane >= off) ws += y;
    }
    if (lane == 63) wsum_sh[wid] = ws;
    __syncthreads();
    u64 w0 = wsum_sh[0], w1 = wsum_sh[1], w2 = wsum_sh[2], w3 = wsum_sh[3];
    u64 wexcl = (wid > 0 ? w0 : 0) + (wid > 1 ? w1 : 0) + (wid > 2 ? w2 : 0);
    u64 texcl = wexcl + ws - sum;
    u64 total = w0 + w1 + w2 + w3;
    u32 tlo = (u32)(total & 0xFFFFFFFFull), thi = (u32)(total >> 32);

    if (vt == 0) {
        if (t == 0) {
            __hip_atomic_store(&status[0], (2ull << 62) | ((u64)thi << 28) | (u64)tlo,
                               __ATOMIC_RELAXED, __HIP_MEMORY_SCOPE_AGENT);
            excl_sh = 0;
            if (ntiles == 1) { out_lo[n] = tlo; if (MODE == 0) out_hi[n] = thi; }
        }
    } else if (wid == 3) {      // wave 3: post partial, then lane-parallel lookback
        if (lane == 0)
            __hip_atomic_store(&status[(size_t)vt * SSTRIDE],
                               (1ull << 62) | ((u64)thi << 28) | (u64)tlo,
                               __ATOMIC_RELAXED, __HIP_MEMORY_SCOPE_AGENT);
        u32 elo = 0, ehi = 0;
        int bidx = vt - 1;
        while (true) {
            int idx = bidx - lane;
            u64 s;
            if (idx >= 0) {
                while (true) {
                    s = __hip_atomic_load(&status[(size_t)idx * SSTRIDE], __ATOMIC_RELAXED,
                                          __HIP_MEMORY_SCOPE_AGENT);
                    if ((s >> 62) != 0ull) break;
                    __builtin_amdgcn_s_sleep(1);
                }
            } else {
                s = 2ull << 62;   // virtual inclusive-0 before the beginning
            }
            u64 bal = __ballot((s >> 62) == 2ull);
            u32 clo, chi;
            if (bal) {
                u32 L = (u32)__ffsll((unsigned long long)bal) - 1u;  // nearest state-2
                clo = ((u32)lane <= L) ? (u32)(s & 0xFFFFFFFull) : 0u;
                chi = ((u32)lane <= L) ? (u32)((s >> 28) & 0xFFFFFFFull) : 0u;
            } else {
                clo = (u32)(s & 0xFFFFFFFull);
                chi = (u32)((s >> 28) & 0xFFFFFFFull);
            }
            #pragma unroll
            for (int off = 1; off < 64; off <<= 1) {
                clo += __shfl_xor(clo, off, 64);
                chi += __shfl_xor(chi, off, 64);
            }
            elo += clo; ehi += chi;
            if (bal) break;
            bidx -= 64;
        }
        if (lane == 0) {
            __hip_atomic_store(&status[(size_t)vt * SSTRIDE],
                (2ull << 62) | ((u64)(thi + ehi) << 28) | (u64)(tlo + elo),
                __ATOMIC_RELAXED, __HIP_MEMORY_SCOPE_AGENT);
            excl_sh = (u64)elo | ((u64)ehi << 32);
            if (vt == ntiles - 1) {
                out_lo[n] = tlo + elo;
                if (MODE == 0) out_hi[n] = thi + ehi;
            }
        }
    }
    __syncthreads();
    u64 run = excl_sh + texcl;
    if (full) {
        #pragma unroll
        for (int q = 0; q < VPT / 4; q++) {
            u32 lo_a[4], hi_a[4];
            #pragma unroll
            for (int e = 0; e < 4; e++) {
                lo_a[e] = (u32)run; hi_a[e] = (u32)(run >> 32);
                run += val_of(v[q * 4 + e]);
            }
            *(uint4*)(out_lo + base + q * 4) = make_uint4(lo_a[0], lo_a[1], lo_a[2], lo_a[3]);
            if (MODE == 0)
                *(uint4*)(out_hi + base + q * 4) = make_uint4(hi_a[0], hi_a[1], hi_a[2], hi_a[3]);
        }
    } else {
        for (int e = 0; e < VPT; e++) {
            int i = base + e;
            if (i < n) {
                out_lo[i] = (u32)run;
                if (MODE == 0) out_hi[i] = (u32)(run >> 32);
                run += val_of(v[e]);
            }
        }
    }
}

// ---------------- stage-1 scatter ----------------
__global__ void k_scatter(const u32* pvid, int n, const u32* starts, u32* cursor, u32* ptbuf)
{
    int i = blockIdx.x * blockDim.x + threadIdx.x;
    if (i >= n) return;
    u32 g = pvid[i];
    if (g == 0xFFFFFFFFu) return;
    u32 pos = atomicAdd(&cursor[g], 1u);
    ptbuf[starts[g] + pos] = (u32)i;
}

// ---------------- fused: per-cell sort + voxel build + roi mask ----------------
__global__ void k_cells(const u32* cnt1, const u32* starts, const u32* flagsc,
                        const u32* roibm, u32* ptbuf, u32* npm, u32* vstart)
{
    int c = blockIdx.x * blockDim.x + threadIdx.x;
    if (c >= NC1) return;
    u32 n = cnt1[c];
    if (!n) return;
    int f = c / C1, lv = c % C1;
    u32 slot = flagsc[c] - flagsc[f * C1];
    if (slot >= MAXV) return;
    int cx = lv % GX1, cy = lv / GX1;
    u32 idx = (u32)f * MAXV + slot;
    u32 s0 = starts[c];
    vstart[idx] = s0;
    u32 bit = (roibm[(size_t)f * (GY1 * RBW) + cy * RBW + (cx >> 5)] >> (cx & 31)) & 1u;
    if (!bit) return;  // npm stays 0 from init
    npm[idx] = n < 32u ? n : 32u;
    // stable order within voxel = ascending point index: insertion sort
    for (u32 a = 1; a < n; a++) {
        u32 v = ptbuf[s0 + a];
        int bp2 = (int)a;
        while (bp2 > 0 && ptbuf[s0 + bp2 - 1] > v) { ptbuf[s0 + bp2] = ptbuf[s0 + bp2 - 1]; bp2--; }
        ptbuf[s0 + bp2] = v;
    }
}

// ---------------- emit kept points, mark fine-voxel bitmap ----------------
__global__ void k_emitkept(const float* P, const u32* npm, const u32* koff, const u32* vstart,
                           const u32* ptbuf, u32* kept, u32* fvid, u32* bitmap)
{
    int idx = blockIdx.x * blockDim.x + threadIdx.x;
    if (idx >= NF * MAXV) return;
    u32 m = npm[idx];
    if (!m) return;
    u32 base = koff[idx];
    u32 vs = vstart[idx];
    u32 f = (u32)idx / MAXV;
    for (u32 r = 0; r < m; r++) {
        u32 pidx = ptbuf[vs + r];
        u32 seq = base + r;
        kept[seq] = pidx;
        const float* p = P + (size_t)pidx * 6;
        float fx = floorf((p[1] - PCX) / VSH);
        float fy = floorf((p[2] - PCY) / VSH);
        float fz = floorf((p[3] - PCZ) / VSH);
        u32 pk = 0xFFFFFFFFu;
        if (fx >= 0.f && fx < (float)GX2 && fy >= 0.f && fy < (float)GY2 &&
            fz >= 0.f && fz < (float)GZ2) {
            u32 vid = ((u32)fz * GY2 + (u32)fy) * GX2 + (u32)fx;
            pk = (f << 25) | vid;
            atomicOr(&bitmap[f * WPF + (vid >> 5)], 1u << (vid & 31));
        }
        fvid[seq] = pk;
    }
}

// ---------------- insert kept seqs into per-voxel 5-min sorted arrays ----------------
__global__ void k_insert(const u32* fvid, const u32* koffend, const u32* bitmap,
                         const u32* wordpref, u32* slotseq)
{
    u32 i = blockIdx.x * blockDim.x + threadIdx.x;
    u32 Mt = koffend[0];
    if (i >= Mt) return;
    u32 pk = fvid[i];
    if (pk == 0xFFFFFFFFu) return;
    u32 f = pk >> 25, vid = pk & 0x1FFFFFFu;
    u32 gw = f * WPF + (vid >> 5);
    u32 slot = wordpref[gw] - wordpref[f * WPF] +
               (u32)__popc(bitmap[gw] & ((1u << (vid & 31)) - 1u));
    if (slot >= (u32)MAXV) return;
    u32* arr = slotseq + (size_t)(f * MAXV + slot) * KK2;
    u32 val = i;
    #pragma unroll
    for (int j = 0; j < KK2; j++) {
        u32 old = atomicMin(&arr[j], val);
        if (old == 0xFFFFFFFFu) break;     // landed in empty slot
        val = old > val ? old : val;       // carry displaced value
    }
}

// ---------------- per-(frame, roi) selection + output ----------------
__global__ void __launch_bounds__(256) k_output(const float* P, const u32* boxp,
    const u32* bitmap, const u32* wordpref, const u32* slotseq, const u32* kept, float* out)
{
    __shared__ u32 rpref_s[MAXROWS];
    __shared__ u32 ssum[256];
    __shared__ int sidx[NSAMP];
    __shared__ float feat[KK2 * NSAMP][5];
    __shared__ u32 pmf[KK2 * NSAMP];
    __shared__ int sel[NSAMP];
    __shared__ int nsel_s;
    __shared__ u32 M_s;

    int bid = blockIdx.x, tid = threadIdx.x;
    int f = bid / RR, r = bid % RR;
    int b = f / TT, t = f % TT;
    const u32* bp = boxp + bid * 12;
    float bx = __uint_as_float(bp[0]);
    float by = __uint_as_float(bp[1]);
    float cr2 = __uint_as_float(bp[2]);
    float zmax = __uint_as_float(bp[3]);
    int Q1x = (int)bp[7], Q1y = (int)bp[8], irad2 = (int)bp[9];

    const u32* bmf = bitmap + (size_t)f * WPF;
    u32 wp_f0 = wordpref[f * WPF];
    u32 nv2u = wordpref[(f + 1) * WPF] - wp_f0;
    int nv2 = (nv2u > (u32)MAXV) ? MAXV : (int)nv2u;

    int cxlo = Q1x - irad2 + 1; if (cxlo < 0) cxlo = 0;
    int cxhi = Q1x + irad2 - 1; if (cxhi > GX2 - 1) cxhi = GX2 - 1;
    int cylo = Q1y - irad2 + 1; if (cylo < 0) cylo = 0;
    int cyhi = Q1y + irad2 - 1; if (cyhi > GY2 - 1) cyhi = GY2 - 1;
    int ny = cyhi - cylo + 1;
    int nrows = (cxlo <= cxhi && cylo <= cyhi) ? GZ2 * ny : 0;
    if (nrows > MAXROWS) nrows = MAXROWS;

    // phase A: per-row match counts via bitmap popcount (blocked per thread)
    u32 myrpref[RPT];
    u32 lsum = 0;
    #pragma unroll
    for (int e = 0; e < RPT; e++) {
        int ri = tid * RPT + e;
        myrpref[e] = lsum;
        if (ri < nrows) {
            int cz = ri / ny, cy = cylo + (ri - cz * ny);
            u32 vlo = ((u32)cz * GY2 + (u32)cy) * GX2 + (u32)cxlo;
            u32 vhi = vlo + (u32)(cxhi - cxlo);
            u32 gwlo = vlo >> 5, gwhi = vhi >> 5;
            u32 c = 0;
            for (u32 gw = gwlo; gw <= gwhi; gw++) {
                u32 w = bmf[gw];
                u32 lob = (gw == gwlo) ? (vlo & 31u) : 0u;
                u32 hib = (gw == gwhi) ? (vhi & 31u) : 31u;
                u32 m = (hib == 31u ? 0xFFFFFFFFu : ((1u << (hib + 1)) - 1u)) & ~((1u << lob) - 1u);
                c += (u32)__popc(w & m);
            }
            lsum += c;
        }
    }
    ssum[tid] = lsum;
    __syncthreads();
    for (int off = 1; off < 256; off <<= 1) {
        u32 y = (tid >= off) ? ssum[tid - off] : 0;
        __syncthreads();
        ssum[tid] += y;
        __syncthreads();
    }
    u32 texcl = ssum[tid] - lsum;
    if (tid == 255) M_s = ssum[255];
    #pragma unroll
    for (int e = 0; e < RPT; e++) {
        int ri = tid * RPT + e;
        if (ri < MAXROWS) rpref_s[ri] = texcl + myrpref[e];
    }
    __syncthreads();

    u32 M = M_s;
    int nt = (int)(M < (u32)NSAMP ? M : (u32)NSAMP);
    // phase B1: tid-th matched voxel in ascending vid order -> slot via wordpref rank
    if (tid < nt) {
        int lo = 0, hi = nrows - 1;
        while (lo < hi) { int m = (lo + hi + 1) >> 1; if (rpref_s[m] <= (u32)tid) lo = m; else hi = m - 1; }
        u32 rem = (u32)tid - rpref_s[lo];
        int cz = lo / ny, cy = cylo + (lo - cz * ny);
        u32 vlo = ((u32)cz * GY2 + (u32)cy) * GX2 + (u32)cxlo;
        u32 vhi = vlo + (u32)(cxhi - cxlo);
        u32 gwlo = vlo >> 5, gwhi = vhi >> 5;
        int slot = 0;
        for (u32 gw = gwlo; gw <= gwhi; gw++) {
            u32 w = bmf[gw];
            u32 lob = (gw == gwlo) ? (vlo & 31u) : 0u;
            u32 hib = (gw == gwhi) ? (vhi & 31u) : 31u;
            u32 m = (hib == 31u ? 0xFFFFFFFFu : ((1u << (hib + 1)) - 1u)) & ~((1u << lob) - 1u);
            u32 wm = w & m;
            u32 pc = (u32)__popc(wm);
            if (rem < pc) {
                for (u32 k = 0; k < rem; k++) wm &= wm - 1u;
                u32 bit = (u32)__ffs(wm) - 1u;
                slot = (int)(wordpref[f * WPF + gw] - wp_f0 + (u32)__popc(w & ((1u << bit) - 1u)));
                break;
            }
            rem -= pc;
        }
        sidx[tid] = slot;
    }
    __syncthreads();
    // phase B2: top_k false-fill with lowest non-matching slot indices
    if (tid == 0) {
        int c = nt, p = 0, s = 0;
        while (c < NSAMP) {
            if (p < nt && sidx[p] == s) { p++; s++; continue; }
            sidx[c++] = s++;
        }
    }
    __syncthreads();

    // phase C: gather sv in flat (k2-major) order, evaluate pm
    for (int j = tid; j < KK2 * NSAMP; j += 256) {
        int k2 = j >> 5, s = j & 31;
        int slot = sidx[s];
        float px = 0.f, py = 0.f, pz = 0.f, pi = 0.f, pt = 0.f;
        if (slot < nv2) {
            u32 seq = slotseq[(size_t)(f * MAXV + slot) * KK2 + k2];
            if (seq != 0xFFFFFFFFu) {
                u32 pidx = kept[seq];
                const float* p = P + (size_t)pidx * 6;
                px = p[1]; py = p[2]; pz = p[3]; pi = p[4]; pt = p[5];
            }
        }
        feat[j][0] = px; feat[j][1] = py; feat[j][2] = pz; feat[j][3] = pi; feat[j][4] = pt;
        float ex = px - bx, ey = py - by;
        pmf[j] = (ex * ex + ey * ey < cr2 && pz <= zmax) ? 1u : 0u;
    }
    __syncthreads();

    // phase D: top_k over pm in flat order
    if (tid == 0) {
        int c = 0;
        for (int j = 0; j < KK2 * NSAMP && c < NSAMP; j++)
            if (pmf[j]) sel[c++] = j;
        nsel_s = c;
    }
    __syncthreads();

    // phase E: write 32 rows x 5 feats
    int obase = ((b * RR + r) * (TT * NSAMP) + t * NSAMP) * 5;
    for (int w = tid; w < NSAMP * 5; w += 256) {
        int row = w / 5, col = w % 5;
        float v = (row < nsel_s) ? feat[sel[row]][col] : 0.f;
        out[obase + w] = v;
    }
}

extern "C" void kernel_launch(void* const* d_in, const int* in_sizes, int n_in,
                              void* d_out, int out_size, void* d_ws, size_t ws_size,
                              hipStream_t stream)
{
    const float* P = (const float*)d_in[0];
    const float* traj = (const float*)d_in[1];
    const float* back = (const float*)d_in[2];
    const unsigned char* vlb = (const unsigned char*)d_in[3];
    float* out = (float*)d_out;
    int N = in_sizes[0] / 6;
    if (N > NMAXP) N = NMAXP;

    char* cur = (char*)d_ws;
    auto carve = [&](size_t bytes) -> char* {
        char* p = cur;
        cur += (bytes + 255) & ~(size_t)255;
        return p;
    };

    // ---- zero zone 1: cnt1 + cursor ----
    char* zoneZ1 = cur;
    u32* cnt1   = (u32*)carve((size_t)NC1 * 4);
    u32* cursor = (u32*)carve((size_t)NC1 * 4);
    size_t z1_bytes = (size_t)(cur - zoneZ1);
    // ---- scan outputs (fully written by scans, no init) ----
    u32* flagsc = (u32*)carve((size_t)(NC1 + 1) * 4);
    u32* starts = (u32*)carve((size_t)(NC1 + 1) * 4);
    // wordpref aliases [cnt1, cursor, flagsc, starts] (18.1MB >= 17MB); those are dead before scan<3>
    u32* wordpref = (u32*)zoneZ1;
    // ---- zero zone 2: npm + roibm + bitmap + scan status + tickets ----
    char* zoneZ2 = cur;
    u32* npm     = (u32*)carve((size_t)NF * MAXV * 4);
    u32* roibm   = (u32*)carve((size_t)NF * GY1 * RBW * 4);
    u32* bitmap  = (u32*)carve((size_t)NF * WPF * 4);
    u64* status  = (u64*)carve((size_t)3 * STN * SSTRIDE * 8);
    u32* tickets = (u32*)carve(64);
    size_t z2_bytes = (size_t)(cur - zoneZ2);
    // ---- 0xFF zone: slotseq ----
    u32* slotseq = (u32*)carve((size_t)NF * MAXV * KK2 * 4);
    size_t ff_bytes = (size_t)(cur - (char*)slotseq);

    u32* pvid   = (u32*)carve((size_t)NMAXP * 4);
    u32* ptbuf  = (u32*)carve((size_t)NMAXP * 4);
    u32* vstart = (u32*)carve((size_t)NF * MAXV * 4);
    u32* koff   = (u32*)carve((size_t)(NF * MAXV + 1) * 4);
    u32* boxp   = (u32*)carve((size_t)NF * RR * 12 * 4);
    u32* kept   = (u32*)carve((size_t)NMAXP * 4);
    u32* fvid   = (u32*)carve((size_t)NMAXP * 4);
    if ((size_t)(cur - (char*)d_ws) > ws_size) return;  // insufficient workspace

    k_init<<<1024, 256, 0, stream>>>((u32*)zoneZ1, (u32)(z1_bytes / 16),
                                     (u32*)zoneZ2, (u32)(z2_bytes / 16),
                                     slotseq, (u32)(ff_bytes / 16));

    k_roipts<<<(N + 255) / 256, 256, 0, stream>>>(P, N, traj, back, vlb, boxp, roibm, pvid, cnt1);

    {   // scan 0: cnt1 -> starts (count prefix) + flagsc (occupancy prefix)
        int n = NC1, nt = (n + TILE - 1) / TILE;
        k_scan_lb<0><<<nt, 256, 0, stream>>>(cnt1, starts, flagsc, status, &tickets[0], n, nt);
    }

    k_scatter<<<(N + 255) / 256, 256, 0, stream>>>(pvid, N, starts, cursor, ptbuf);
    k_cells<<<(NC1 + 255) / 256, 256, 0, stream>>>(cnt1, starts, flagsc, roibm, ptbuf, npm, vstart);

    {   // scan 1: npm -> koff
        int n = NF * MAXV, nt = (n + TILE - 1) / TILE;
        k_scan_lb<1><<<nt, 256, 0, stream>>>(npm, koff, nullptr, status + (size_t)STN * SSTRIDE, &tickets[1], n, nt);
    }

    k_emitkept<<<(NF * MAXV + 255) / 256, 256, 0, stream>>>(P, npm, koff, vstart, ptbuf, kept, fvid, bitmap);

    {   // scan 3: bitmap -> wordpref (popcount prefix)
        int n = NF * WPF, nt = (n + TILE - 1) / TILE;
        k_scan_lb<3><<<nt, 256, 0, stream>>>(bitmap, wordpref, nullptr, status + (size_t)2 * STN * SSTRIDE, &tickets[2], n, nt);
    }

    k_insert<<<NPAD / 256, 256, 0, stream>>>(fvid, koff + NF * MAXV, bitmap, wordpref, slotseq);
    k_output<<<NF * RR, 256, 0, stream>>>(P, boxp, bitmap, wordpref, slotseq, kept, out);
}

// Round 7
// 132.045 us; speedup vs baseline: 9.1900x; 1.0035x over previous
//
#include <hip/hip_runtime.h>

typedef unsigned int u32;
typedef unsigned long long u64;

#define BB 2
#define TT 4
#define NF 8            // B*T frames
#define RR 128          // rois
#define NSAMP 32        // num_sample
#define KK2 5           // max points per fine voxel
#define MAXV 50000
#define GX1 376
#define GY1 376
#define C1 141376       // GX1*GY1 (gz=1)
#define NC1 1131008     // NF*C1
#define GX2 752
#define GY2 752
#define GZ2 30
#define WPF 530160      // bitmap words per frame = GX2*GY2*GZ2/32
#define RBW 12          // roibm words per row (376 bits)
#define NPAD 262144
#define NMAXP 262144
#define MAXROWS 1536
#define RPT 6           // rows per thread in k_output (256*6 = 1536)
#define VPT 32          // scan words per thread
#define TILE 8192       // scan words per tile (256*VPT)
#define STN 576         // status entries per scan (>= max tiles 518)
#define SSTRIDE 16      // u64s between status entries (128B cache-line pad)

#define PCX (-75.2f)
#define PCY (-75.2f)
#define PCZ (-2.0f)
#define VS1 0.4f
#define VSH 0.2f
#define VZ1 6.0f

// ---------------- workspace init ----------------
// z0: zero segment; f2: 0xFF segment. Counts are in uint4 units.
__global__ void k_init(u32* z0, u32 n0, u32* f2, u32 n2)
{
    u32 tid = blockIdx.x * blockDim.x + threadIdx.x;
    u32 stride = gridDim.x * blockDim.x;
    uint4 zz = make_uint4(0u, 0u, 0u, 0u);
    uint4 fv = make_uint4(~0u, ~0u, ~0u, ~0u);
    for (u32 i = tid; i < n0; i += stride) ((uint4*)z0)[i] = zz;
    for (u32 i = tid; i < n2; i += stride) ((uint4*)f2)[i] = fv;
}

// ---------------- fused: box params + roi raster + stage-1 point voxelize ----------------
// boxp layout per (f,r), 12 u32 words:
// 0:bx 1:by 2:cur_r^2 3:zmax (floats); 4:Qx 5:Qy 6:irad 7:Q1x 8:Q1y 9:irad2 (ints)
__global__ void k_roipts(const float* P, int n, const float* traj, const float* back,
                         const unsigned char* vlb, u32* boxp, u32* roibm, u32* pvid, u32* cnt1)
{
    int i = blockIdx.x * blockDim.x + threadIdx.x;
    if (i < NF * RR) {
        // detect valid_length storage: int32 (0/1 -> bytes at %4!=0 are 0) vs uint8/bool
        bool isU8 = false;
        for (int k = 1; k < 64; k++)
            if ((k & 3) && vlb[k]) isU8 = true;
        bool vl = isU8 ? (vlb[i] != 0) : (((const int*)vlb)[i] != 0);
        const float* tb = traj + i * 7;
        const float* bb = back + i * 7;
        float bx = vl ? (tb[0] + bb[0]) * 0.5f : bb[0];
        float by = vl ? (tb[1] + bb[1]) * 0.5f : bb[1];
        float bz = bb[2], dx = bb[3], dy = bb[4], dz = bb[5];
        float hx = dx * 0.5f, hy = dy * 0.5f;
        float r0 = sqrtf(hx * hx + hy * hy);
        float radf = ceilf(r0 * 1.1f / 0.4f);
        float curr = r0 * 1.1f;
        u32* bp = boxp + i * 12;
        int Qx = (int)floorf((bx - PCX) / VS1);
        int Qy = (int)floorf((by - PCY) / VS1);
        int ir = (int)radf;
        bp[0] = __float_as_uint(bx);
        bp[1] = __float_as_uint(by);
        bp[2] = __float_as_uint(curr * curr);
        bp[3] = __float_as_uint(bz + dz * 0.6f);
        bp[4] = (u32)Qx;
        bp[5] = (u32)Qy;
        bp[6] = (u32)ir;
        bp[7] = (u32)(int)floorf((bx - PCX) / VSH);
        bp[8] = (u32)(int)floorf((by - PCY) / VSH);
        bp[9] = (u32)(2 * ir);

        int f = i / RR;
        int xlo = Qx - ir + 1; if (xlo < 0) xlo = 0;
        int xhi = Qx + ir - 1; if (xhi > GX1 - 1) xhi = GX1 - 1;
        int ylo = Qy - ir + 1; if (ylo < 0) ylo = 0;
        int yhi = Qy + ir - 1; if (yhi > GY1 - 1) yhi = GY1 - 1;
        if (xlo <= xhi && ylo <= yhi) {
            int w0 = xlo >> 5, w1 = xhi >> 5;
            for (int cy = ylo; cy <= yhi; cy++) {
                u32* row = roibm + (size_t)f * (GY1 * RBW) + cy * RBW;
                for (int w = w0; w <= w1; w++) {
                    int lo = xlo - (w << 5); if (lo < 0) lo = 0;
                    int hi = xhi - (w << 5); if (hi > 31) hi = 31;
                    u32 m = (hi == 31 ? 0xFFFFFFFFu : ((1u << (hi + 1)) - 1u)) & ~((1u << lo) - 1u);
                    atomicOr(&row[w], m);
                }
            }
        }
    }
    if (i < n) {
        const float* p = P + (size_t)i * 6;
        float bsf = p[0], x = p[1], y = p[2], z = p[3], tt = p[5];
        u32 g = 0xFFFFFFFFu;
        int b = (int)bsf;
        int t = (int)floorf(tt * 10.0f + 0.5f);
        if (bsf == (float)b && b >= 0 && b < BB && t >= 0 && t < TT &&
            fabsf(tt - 0.1f * (float)t) < 0.001f) {
            float fx = floorf((x - PCX) / VS1);
            float fy = floorf((y - PCY) / VS1);
            float fz = floorf((z - PCZ) / VZ1);
            if (fx >= 0.f && fx < (float)GX1 && fy >= 0.f && fy < (float)GY1 && fz == 0.f) {
                g = (u32)((b * TT + t) * C1) + (u32)fy * GX1 + (u32)fx;
            }
        }
        pvid[i] = g;
        if (g != 0xFFFFFFFFu) atomicAdd(&cnt1[g], 1u);
    }
}

// ---------------- single-pass decoupled-lookback exclusive scan ----------------
// MODE 4: in=cnt1 + roibm mask -> lo:prefix(count), hi:prefix(mask ? min(count,32) : 0)
// MODE 3: in=bitmap            -> lo:prefix(popcount)
// status word (self-contained, single u64 => RELAXED atomics suffice):
//   state(2b)<<62 | hi(28b)<<28 | lo(28b); all running sums < 2^28.
// Entries padded to 128B (SSTRIDE) to avoid LLC line contention among pollers.
// Ticket-ordered tile assignment guarantees forward progress.
// Lookback is WAVE-PARALLEL: wave 3's 64 lanes poll 64 predecessors per round.
template <int MODE>
__global__ void __launch_bounds__(256) k_scan_lb(const u32* in, const u32* roibm,
                                                 u32* out_lo, u32* out_hi,
                                                 u64* status, u32* ticket, int n, int ntiles)
{
    __shared__ u64 wsum_sh[4];
    __shared__ u64 excl_sh;
    __shared__ u32 vt_sh;
    int t = threadIdx.x;
    int lane = t & 63, wid = t >> 6;
    if (t == 0) vt_sh = atomicAdd(ticket, 1u);
    __syncthreads();
    int vt = (int)vt_sh;
    int base = vt * TILE + t * VPT;
    u32 v[VPT];
    bool full = (base + VPT <= n);
    if (full) {
        #pragma unroll
        for (int q = 0; q < VPT / 4; q++) {
            uint4 a = *(const uint4*)(in + base + q * 4);
            v[q * 4 + 0] = a.x; v[q * 4 + 1] = a.y; v[q * 4 + 2] = a.z; v[q * 4 + 3] = a.w;
        }
    } else {
        #pragma unroll
        for (int e = 0; e < VPT; e++) { int i = base + e; v[e] = (i < n) ? in[i] : 0u; }
    }
    auto val_of = [&](u32 x, int i) -> u64 {
        if (MODE == 4) {
            u32 cnt = x;
            u32 kept = 0;
            if (cnt) {
                int f = i / C1, lv = i - f * C1;
                int cy = lv / GX1, cx = lv - cy * GX1;
                u32 bit = (roibm[(size_t)f * (GY1 * RBW) + cy * RBW + (cx >> 5)] >> (cx & 31)) & 1u;
                kept = bit ? (cnt < 32u ? cnt : 32u) : 0u;
            }
            return (u64)cnt | ((u64)kept << 32);
        } else {
            return (u64)(u32)__popc(x);
        }
    };
    u64 sum = 0;
    #pragma unroll
    for (int e = 0; e < VPT; e++) sum += val_of(v[e], base + e);
    // wave-level inclusive scan (no barriers)
    u64 ws = sum;
    #pragma unroll
    for (int off = 1; off < 64; off <<= 1) {
        u64 y = __shfl_up(ws, off, 64);
        if (lane >= off) ws += y;
    }
    if (lane == 63) wsum_sh[wid] = ws;
    __syncthreads();
    u64 w0 = wsum_sh[0], w1 = wsum_sh[1], w2 = wsum_sh[2], w3 = wsum_sh[3];
    u64 wexcl = (wid > 0 ? w0 : 0) + (wid > 1 ? w1 : 0) + (wid > 2 ? w2 : 0);
    u64 texcl = wexcl + ws - sum;
    u64 total = w0 + w1 + w2 + w3;
    u32 tlo = (u32)(total & 0xFFFFFFFFull), thi = (u32)(total >> 32);

    if (vt == 0) {
        if (t == 0) {
            __hip_atomic_store(&status[0], (2ull << 62) | ((u64)thi << 28) | (u64)tlo,
                               __ATOMIC_RELAXED, __HIP_MEMORY_SCOPE_AGENT);
            excl_sh = 0;
            if (ntiles == 1) { out_lo[n] = tlo; if (MODE == 4) out_hi[n] = thi; }
        }
    } else if (wid == 3) {      // wave 3: post partial, then lane-parallel lookback
        if (lane == 0)
            __hip_atomic_store(&status[(size_t)vt * SSTRIDE],
                               (1ull << 62) | ((u64)thi << 28) | (u64)tlo,
                               __ATOMIC_RELAXED, __HIP_MEMORY_SCOPE_AGENT);
        u32 elo = 0, ehi = 0;
        int bidx = vt - 1;
        while (true) {
            int idx = bidx - lane;
            u64 s;
            if (idx >= 0) {
                while (true) {
                    s = __hip_atomic_load(&status[(size_t)idx * SSTRIDE], __ATOMIC_RELAXED,
                                          __HIP_MEMORY_SCOPE_AGENT);
                    if ((s >> 62) != 0ull) break;
                    __builtin_amdgcn_s_sleep(1);
                }
            } else {
                s = 2ull << 62;   // virtual inclusive-0 before the beginning
            }
            u64 bal = __ballot((s >> 62) == 2ull);
            u32 clo, chi;
            if (bal) {
                u32 L = (u32)__ffsll((unsigned long long)bal) - 1u;  // nearest state-2
                clo = ((u32)lane <= L) ? (u32)(s & 0xFFFFFFFull) : 0u;
                chi = ((u32)lane <= L) ? (u32)((s >> 28) & 0xFFFFFFFull) : 0u;
            } else {
                clo = (u32)(s & 0xFFFFFFFull);
                chi = (u32)((s >> 28) & 0xFFFFFFFull);
            }
            #pragma unroll
            for (int off = 1; off < 64; off <<= 1) {
                clo += __shfl_xor(clo, off, 64);
                chi += __shfl_xor(chi, off, 64);
            }
            elo += clo; ehi += chi;
            if (bal) break;
            bidx -= 64;
        }
        if (lane == 0) {
            __hip_atomic_store(&status[(size_t)vt * SSTRIDE],
                (2ull << 62) | ((u64)(thi + ehi) << 28) | (u64)(tlo + elo),
                __ATOMIC_RELAXED, __HIP_MEMORY_SCOPE_AGENT);
            excl_sh = (u64)elo | ((u64)ehi << 32);
            if (vt == ntiles - 1) {
                out_lo[n] = tlo + elo;
                if (MODE == 4) out_hi[n] = thi + ehi;
            }
        }
    }
    __syncthreads();
    u64 run = excl_sh + texcl;
    if (full) {
        #pragma unroll
        for (int q = 0; q < VPT / 4; q++) {
            u32 lo_a[4], hi_a[4];
            #pragma unroll
            for (int e = 0; e < 4; e++) {
                lo_a[e] = (u32)run; hi_a[e] = (u32)(run >> 32);
                run += val_of(v[q * 4 + e], base + q * 4 + e);
            }
            *(uint4*)(out_lo + base + q * 4) = make_uint4(lo_a[0], lo_a[1], lo_a[2], lo_a[3]);
            if (MODE == 4)
                *(uint4*)(out_hi + base + q * 4) = make_uint4(hi_a[0], hi_a[1], hi_a[2], hi_a[3]);
        }
    } else {
        for (int e = 0; e < VPT; e++) {
            int i = base + e;
            if (i < n) {
                out_lo[i] = (u32)run;
                if (MODE == 4) out_hi[i] = (u32)(run >> 32);
                run += val_of(v[e], i);
            }
        }
    }
}

// ---------------- stage-1 scatter (starts doubles as cursor; old value = abs pos) ----------------
__global__ void k_scatter(const u32* pvid, int n, u32* starts, u32* ptbuf)
{
    int i = blockIdx.x * blockDim.x + threadIdx.x;
    if (i >= n) return;
    u32 g = pvid[i];
    if (g == 0xFFFFFFFFu) return;
    u32 pos = atomicAdd(&starts[g], 1u);
    ptbuf[pos] = (u32)i;
}

// ---------------- fused: per-cell sort + emit kept points + fine-voxel bitmap ----------------
__global__ void k_emit2(const float* P, const u32* cnt1, const u32* starts, const u32* koffc,
                        const u32* roibm, u32* ptbuf, u32* kept, u32* fvid, u32* bitmap)
{
    int c = blockIdx.x * blockDim.x + threadIdx.x;
    if (c >= NC1) return;
    u32 n = cnt1[c];
    if (!n) return;
    int f = c / C1, lv = c - f * C1;
    int cy = lv / GX1, cx = lv - cy * GX1;
    u32 bit = (roibm[(size_t)f * (GY1 * RBW) + cy * RBW + (cx >> 5)] >> (cx & 31)) & 1u;
    if (!bit) return;
    u32 s0 = starts[c] - n;   // starts was advanced by n during scatter
    // stable order within voxel = ascending point index: insertion sort
    for (u32 a = 1; a < n; a++) {
        u32 v = ptbuf[s0 + a];
        int bp2 = (int)a;
        while (bp2 > 0 && ptbuf[s0 + bp2 - 1] > v) { ptbuf[s0 + bp2] = ptbuf[s0 + bp2 - 1]; bp2--; }
        ptbuf[s0 + bp2] = v;
    }
    u32 m = n < 32u ? n : 32u;
    u32 base = koffc[c];
    for (u32 r = 0; r < m; r++) {
        u32 pidx = ptbuf[s0 + r];
        u32 seq = base + r;
        kept[seq] = pidx;
        const float* p = P + (size_t)pidx * 6;
        float fx = floorf((p[1] - PCX) / VSH);
        float fy = floorf((p[2] - PCY) / VSH);
        float fz = floorf((p[3] - PCZ) / VSH);
        u32 pk = 0xFFFFFFFFu;
        if (fx >= 0.f && fx < (float)GX2 && fy >= 0.f && fy < (float)GY2 &&
            fz >= 0.f && fz < (float)GZ2) {
            u32 vid = ((u32)fz * GY2 + (u32)fy) * GX2 + (u32)fx;
            pk = ((u32)f << 25) | vid;
            atomicOr(&bitmap[f * WPF + (vid >> 5)], 1u << (vid & 31));
        }
        fvid[seq] = pk;
    }
}

// ---------------- insert kept seqs into per-voxel 5-min sorted arrays ----------------
__global__ void k_insert(const u32* fvid, const u32* koffend, const u32* bitmap,
                         const u32* wordpref, u32* slotseq)
{
    u32 i = blockIdx.x * blockDim.x + threadIdx.x;
    u32 Mt = koffend[0];
    if (i >= Mt) return;
    u32 pk = fvid[i];
    if (pk == 0xFFFFFFFFu) return;
    u32 f = pk >> 25, vid = pk & 0x1FFFFFFu;
    u32 gw = f * WPF + (vid >> 5);
    u32 slot = wordpref[gw] - wordpref[f * WPF] +
               (u32)__popc(bitmap[gw] & ((1u << (vid & 31)) - 1u));
    if (slot >= (u32)MAXV) return;
    u32* arr = slotseq + (size_t)(f * MAXV + slot) * KK2;
    u32 val = i;
    #pragma unroll
    for (int j = 0; j < KK2; j++) {
        u32 old = atomicMin(&arr[j], val);
        if (old == 0xFFFFFFFFu) break;     // landed in empty slot
        val = old > val ? old : val;       // carry displaced value
    }
}

// ---------------- per-(frame, roi) selection + output ----------------
__global__ void __launch_bounds__(256) k_output(const float* P, const u32* boxp,
    const u32* bitmap, const u32* wordpref, const u32* slotseq, const u32* kept, float* out)
{
    __shared__ u32 rpref_s[MAXROWS];
    __shared__ u32 ssum[256];
    __shared__ int sidx[NSAMP];
    __shared__ float feat[KK2 * NSAMP][5];
    __shared__ u32 pmf[KK2 * NSAMP];
    __shared__ int sel[NSAMP];
    __shared__ int nsel_s;
    __shared__ u32 M_s;

    int bid = blockIdx.x, tid = threadIdx.x;
    int f = bid / RR, r = bid % RR;
    int b = f / TT, t = f % TT;
    const u32* bp = boxp + bid * 12;
    float bx = __uint_as_float(bp[0]);
    float by = __uint_as_float(bp[1]);
    float cr2 = __uint_as_float(bp[2]);
    float zmax = __uint_as_float(bp[3]);
    int Q1x = (int)bp[7], Q1y = (int)bp[8], irad2 = (int)bp[9];

    const u32* bmf = bitmap + (size_t)f * WPF;
    u32 wp_f0 = wordpref[f * WPF];
    u32 nv2u = wordpref[(f + 1) * WPF] - wp_f0;
    int nv2 = (nv2u > (u32)MAXV) ? MAXV : (int)nv2u;

    int cxlo = Q1x - irad2 + 1; if (cxlo < 0) cxlo = 0;
    int cxhi = Q1x + irad2 - 1; if (cxhi > GX2 - 1) cxhi = GX2 - 1;
    int cylo = Q1y - irad2 + 1; if (cylo < 0) cylo = 0;
    int cyhi = Q1y + irad2 - 1; if (cyhi > GY2 - 1) cyhi = GY2 - 1;
    int ny = cyhi - cylo + 1;
    int nrows = (cxlo <= cxhi && cylo <= cyhi) ? GZ2 * ny : 0;
    if (nrows > MAXROWS) nrows = MAXROWS;

    // phase A: per-row match counts via bitmap popcount (blocked per thread)
    u32 myrpref[RPT];
    u32 lsum = 0;
    #pragma unroll
    for (int e = 0; e < RPT; e++) {
        int ri = tid * RPT + e;
        myrpref[e] = lsum;
        if (ri < nrows) {
            int cz = ri / ny, cy = cylo + (ri - cz * ny);
            u32 vlo = ((u32)cz * GY2 + (u32)cy) * GX2 + (u32)cxlo;
            u32 vhi = vlo + (u32)(cxhi - cxlo);
            u32 gwlo = vlo >> 5, gwhi = vhi >> 5;
            u32 c = 0;
            for (u32 gw = gwlo; gw <= gwhi; gw++) {
                u32 w = bmf[gw];
                u32 lob = (gw == gwlo) ? (vlo & 31u) : 0u;
                u32 hib = (gw == gwhi) ? (vhi & 31u) : 31u;
                u32 m = (hib == 31u ? 0xFFFFFFFFu : ((1u << (hib + 1)) - 1u)) & ~((1u << lob) - 1u);
                c += (u32)__popc(w & m);
            }
            lsum += c;
        }
    }
    ssum[tid] = lsum;
    __syncthreads();
    for (int off = 1; off < 256; off <<= 1) {
        u32 y = (tid >= off) ? ssum[tid - off] : 0;
        __syncthreads();
        ssum[tid] += y;
        __syncthreads();
    }
    u32 texcl = ssum[tid] - lsum;
    if (tid == 255) M_s = ssum[255];
    #pragma unroll
    for (int e = 0; e < RPT; e++) {
        int ri = tid * RPT + e;
        if (ri < MAXROWS) rpref_s[ri] = texcl + myrpref[e];
    }
    __syncthreads();

    u32 M = M_s;
    int nt = (int)(M < (u32)NSAMP ? M : (u32)NSAMP);
    // phase B1: tid-th matched voxel in ascending vid order -> slot via wordpref rank
    if (tid < nt) {
        int lo = 0, hi = nrows - 1;
        while (lo < hi) { int m = (lo + hi + 1) >> 1; if (rpref_s[m] <= (u32)tid) lo = m; else hi = m - 1; }
        u32 rem = (u32)tid - rpref_s[lo];
        int cz = lo / ny, cy = cylo + (lo - cz * ny);
        u32 vlo = ((u32)cz * GY2 + (u32)cy) * GX2 + (u32)cxlo;
        u32 vhi = vlo + (u32)(cxhi - cxlo);
        u32 gwlo = vlo >> 5, gwhi = vhi >> 5;
        int slot = 0;
        for (u32 gw = gwlo; gw <= gwhi; gw++) {
            u32 w = bmf[gw];
            u32 lob = (gw == gwlo) ? (vlo & 31u) : 0u;
            u32 hib = (gw == gwhi) ? (vhi & 31u) : 31u;
            u32 m = (hib == 31u ? 0xFFFFFFFFu : ((1u << (hib + 1)) - 1u)) & ~((1u << lob) - 1u);
            u32 wm = w & m;
            u32 pc = (u32)__popc(wm);
            if (rem < pc) {
                for (u32 k = 0; k < rem; k++) wm &= wm - 1u;
                u32 bit = (u32)__ffs(wm) - 1u;
                slot = (int)(wordpref[f * WPF + gw] - wp_f0 + (u32)__popc(w & ((1u << bit) - 1u)));
                break;
            }
            rem -= pc;
        }
        sidx[tid] = slot;
    }
    __syncthreads();
    // phase B2: top_k false-fill with lowest non-matching slot indices
    if (tid == 0) {
        int c = nt, p = 0, s = 0;
        while (c < NSAMP) {
            if (p < nt && sidx[p] == s) { p++; s++; continue; }
            sidx[c++] = s++;
        }
    }
    __syncthreads();

    // phase C: gather sv in flat (k2-major) order, evaluate pm
    for (int j = tid; j < KK2 * NSAMP; j += 256) {
        int k2 = j >> 5, s = j & 31;
        int slot = sidx[s];
        float px = 0.f, py = 0.f, pz = 0.f, pi = 0.f, pt = 0.f;
        if (slot < nv2) {
            u32 seq = slotseq[(size_t)(f * MAXV + slot) * KK2 + k2];
            if (seq != 0xFFFFFFFFu) {
                u32 pidx = kept[seq];
                const float* p = P + (size_t)pidx * 6;
                px = p[1]; py = p[2]; pz = p[3]; pi = p[4]; pt = p[5];
            }
        }
        feat[j][0] = px; feat[j][1] = py; feat[j][2] = pz; feat[j][3] = pi; feat[j][4] = pt;
        float ex = px - bx, ey = py - by;
        pmf[j] = (ex * ex + ey * ey < cr2 && pz <= zmax) ? 1u : 0u;
    }
    __syncthreads();

    // phase D: top_k over pm in flat order
    if (tid == 0) {
        int c = 0;
        for (int j = 0; j < KK2 * NSAMP && c < NSAMP; j++)
            if (pmf[j]) sel[c++] = j;
        nsel_s = c;
    }
    __syncthreads();

    // phase E: write 32 rows x 5 feats
    int obase = ((b * RR + r) * (TT * NSAMP) + t * NSAMP) * 5;
    for (int w = tid; w < NSAMP * 5; w += 256) {
        int row = w / 5, col = w % 5;
        float v = (row < nsel_s) ? feat[sel[row]][col] : 0.f;
        out[obase + w] = v;
    }
}

extern "C" void kernel_launch(void* const* d_in, const int* in_sizes, int n_in,
                              void* d_out, int out_size, void* d_ws, size_t ws_size,
                              hipStream_t stream)
{
    const float* P = (const float*)d_in[0];
    const float* traj = (const float*)d_in[1];
    const float* back = (const float*)d_in[2];
    const unsigned char* vlb = (const unsigned char*)d_in[3];
    float* out = (float*)d_out;
    int N = in_sizes[0] / 6;
    if (N > NMAXP) N = NMAXP;

    char* cur = (char*)d_ws;
    auto carve = [&](size_t bytes) -> char* {
        char* p = cur;
        cur += (bytes + 255) & ~(size_t)255;
        return p;
    };

    // ---- zero zone: cnt1 + roibm + bitmap + scan status + tickets ----
    char* zoneZ = cur;
    u32* cnt1    = (u32*)carve((size_t)NC1 * 4);
    u32* roibm   = (u32*)carve((size_t)NF * GY1 * RBW * 4);
    u32* bitmap  = (u32*)carve((size_t)NF * WPF * 4);
    u64* status  = (u64*)carve((size_t)2 * STN * SSTRIDE * 8);
    u32* tickets = (u32*)carve(64);
    size_t z_bytes = (size_t)(cur - zoneZ);
    // ---- 0xFF zone: slotseq ----
    u32* slotseq = (u32*)carve((size_t)NF * MAXV * KK2 * 4);
    size_t ff_bytes = (size_t)(cur - (char*)slotseq);

    // ---- fully-written by scans / kernels (no init) ----
    u32* starts   = (u32*)carve((size_t)(NC1 + 1) * 4);
    u32* koffc    = (u32*)carve((size_t)(NC1 + 1) * 4);
    u32* wordpref = (u32*)carve((size_t)(NF * WPF + 1) * 4);
    u32* pvid     = (u32*)carve((size_t)NMAXP * 4);
    u32* ptbuf    = (u32*)carve((size_t)NMAXP * 4);
    u32* boxp     = (u32*)carve((size_t)NF * RR * 12 * 4);
    u32* kept     = (u32*)carve((size_t)NMAXP * 4);
    u32* fvid     = (u32*)carve((size_t)NMAXP * 4);
    if ((size_t)(cur - (char*)d_ws) > ws_size) return;  // insufficient workspace

    k_init<<<1024, 256, 0, stream>>>((u32*)zoneZ, (u32)(z_bytes / 16),
                                     slotseq, (u32)(ff_bytes / 16));

    k_roipts<<<(N + 255) / 256, 256, 0, stream>>>(P, N, traj, back, vlb, boxp, roibm, pvid, cnt1);

    {   // scan 4: cnt1 (+roibm mask) -> starts (count prefix) + koffc (masked capped prefix)
        int n = NC1, nt = (n + TILE - 1) / TILE;
        k_scan_lb<4><<<nt, 256, 0, stream>>>(cnt1, roibm, starts, koffc, status, &tickets[0], n, nt);
    }

    k_scatter<<<(N + 255) / 256, 256, 0, stream>>>(pvid, N, starts, ptbuf);
    k_emit2<<<(NC1 + 255) / 256, 256, 0, stream>>>(P, cnt1, starts, koffc, roibm, ptbuf, kept, fvid, bitmap);

    {   // scan 3: bitmap -> wordpref (popcount prefix)
        int n = NF * WPF, nt = (n + TILE - 1) / TILE;
        k_scan_lb<3><<<nt, 256, 0, stream>>>(bitmap, nullptr, wordpref, nullptr,
                                             status + (size_t)STN * SSTRIDE, &tickets[1], n, nt);
    }

    k_insert<<<NPAD / 256, 256, 0, stream>>>(fvid, koffc + NC1, bitmap, wordpref, slotseq);
    k_output<<<NF * RR, 256, 0, stream>>>(P, boxp, bitmap, wordpref, slotseq, kept, out);
}

// Round 9
// 131.645 us; speedup vs baseline: 9.2179x; 1.0030x over previous
//
#include <hip/hip_runtime.h>

typedef unsigned int u32;
typedef unsigned long long u64;

#define BB 2
#define TT 4
#define NF 8            // B*T frames
#define RR 128          // rois
#define NSAMP 32        // num_sample
#define KK2 5           // max points per fine voxel
#define MAXV 50000
#define GX1 376
#define GY1 376
#define C1 141376       // GX1*GY1 (gz=1)
#define NC1 1131008     // NF*C1
#define GX2 752
#define GY2 752
#define GZ2 30
#define WPF 530160      // bitmap words per frame = GX2*GY2*GZ2/32
#define RBW 12          // roibm words per row (376 bits)
#define NPAD 262144
#define NMAXP 262144
#define MAXROWS 1536
#define RPT 6           // rows per thread in k_output (256*6 = 1536)
#define VPT 32          // scan words per thread
#define TILE 8192       // scan words per tile (256*VPT)
#define STN 576         // status entries per scan (>= max tiles 518)
#define SSTRIDE 16      // u64s between status entries (128B cache-line pad)

#define PCX (-75.2f)
#define PCY (-75.2f)
#define PCZ (-2.0f)
#define VS1 0.4f
#define VSH 0.2f
#define VZ1 6.0f

// ---------------- workspace init ----------------
// z0: zero segment; f2: 0xFF segment. Counts are in uint4 units.
__global__ void k_init(u32* z0, u32 n0, u32* f2, u32 n2)
{
    u32 tid = blockIdx.x * blockDim.x + threadIdx.x;
    u32 stride = gridDim.x * blockDim.x;
    uint4 zz = make_uint4(0u, 0u, 0u, 0u);
    uint4 fv = make_uint4(~0u, ~0u, ~0u, ~0u);
    for (u32 i = tid; i < n0; i += stride) ((uint4*)z0)[i] = zz;
    for (u32 i = tid; i < n2; i += stride) ((uint4*)f2)[i] = fv;
}

// ---------------- fused: box params + roi raster + stage-1 voxelize + fine-vid precompute ----
// boxp layout per (f,r), 12 u32 words:
// 0:bx 1:by 2:cur_r^2 3:zmax (floats); 4:Qx 5:Qy 6:irad 7:Q1x 8:Q1y 9:irad2 (ints)
__global__ void k_roipts(const float* P, int n, const float* traj, const float* back,
                         const unsigned char* vlb, u32* boxp, u32* roibm, u32* pvid,
                         u32* pfv, u32* cnt1)
{
    int i = blockIdx.x * blockDim.x + threadIdx.x;
    if (i < NF * RR) {
        // detect valid_length storage: int32 (0/1 -> bytes at %4!=0 are 0) vs uint8/bool
        bool isU8 = false;
        for (int k = 1; k < 64; k++)
            if ((k & 3) && vlb[k]) isU8 = true;
        bool vl = isU8 ? (vlb[i] != 0) : (((const int*)vlb)[i] != 0);
        const float* tb = traj + i * 7;
        const float* bb = back + i * 7;
        float bx = vl ? (tb[0] + bb[0]) * 0.5f : bb[0];
        float by = vl ? (tb[1] + bb[1]) * 0.5f : bb[1];
        float bz = bb[2], dx = bb[3], dy = bb[4], dz = bb[5];
        float hx = dx * 0.5f, hy = dy * 0.5f;
        float r0 = sqrtf(hx * hx + hy * hy);
        float radf = ceilf(r0 * 1.1f / 0.4f);
        float curr = r0 * 1.1f;
        u32* bp = boxp + i * 12;
        int Qx = (int)floorf((bx - PCX) / VS1);
        int Qy = (int)floorf((by - PCY) / VS1);
        int ir = (int)radf;
        bp[0] = __float_as_uint(bx);
        bp[1] = __float_as_uint(by);
        bp[2] = __float_as_uint(curr * curr);
        bp[3] = __float_as_uint(bz + dz * 0.6f);
        bp[4] = (u32)Qx;
        bp[5] = (u32)Qy;
        bp[6] = (u32)ir;
        bp[7] = (u32)(int)floorf((bx - PCX) / VSH);
        bp[8] = (u32)(int)floorf((by - PCY) / VSH);
        bp[9] = (u32)(2 * ir);

        int f = i / RR;
        int xlo = Qx - ir + 1; if (xlo < 0) xlo = 0;
        int xhi = Qx + ir - 1; if (xhi > GX1 - 1) xhi = GX1 - 1;
        int ylo = Qy - ir + 1; if (ylo < 0) ylo = 0;
        int yhi = Qy + ir - 1; if (yhi > GY1 - 1) yhi = GY1 - 1;
        if (xlo <= xhi && ylo <= yhi) {
            int w0 = xlo >> 5, w1 = xhi >> 5;
            for (int cy = ylo; cy <= yhi; cy++) {
                u32* row = roibm + (size_t)f * (GY1 * RBW) + cy * RBW;
                for (int w = w0; w <= w1; w++) {
                    int lo = xlo - (w << 5); if (lo < 0) lo = 0;
                    int hi = xhi - (w << 5); if (hi > 31) hi = 31;
                    u32 m = (hi == 31 ? 0xFFFFFFFFu : ((1u << (hi + 1)) - 1u)) & ~((1u << lo) - 1u);
                    atomicOr(&row[w], m);
                }
            }
        }
    }
    if (i < n) {
        const float* p = P + (size_t)i * 6;
        float bsf = p[0], x = p[1], y = p[2], z = p[3], tt = p[5];
        u32 g = 0xFFFFFFFFu;
        u32 pk = 0xFFFFFFFFu;
        int b = (int)bsf;
        int t = (int)floorf(tt * 10.0f + 0.5f);
        if (bsf == (float)b && b >= 0 && b < BB && t >= 0 && t < TT &&
            fabsf(tt - 0.1f * (float)t) < 0.001f) {
            float fx = floorf((x - PCX) / VS1);
            float fy = floorf((y - PCY) / VS1);
            float fz = floorf((z - PCZ) / VZ1);
            if (fx >= 0.f && fx < (float)GX1 && fy >= 0.f && fy < (float)GY1 && fz == 0.f) {
                g = (u32)((b * TT + t) * C1) + (u32)fy * GX1 + (u32)fx;
                // fine-grid vid precompute (same bounds; used at emission)
                float fx2 = floorf((x - PCX) / VSH);
                float fy2 = floorf((y - PCY) / VSH);
                float fz2 = floorf((z - PCZ) / VSH);
                if (fx2 >= 0.f && fx2 < (float)GX2 && fy2 >= 0.f && fy2 < (float)GY2 &&
                    fz2 >= 0.f && fz2 < (float)GZ2) {
                    u32 vid = ((u32)fz2 * GY2 + (u32)fy2) * GX2 + (u32)fx2;
                    pk = ((u32)(b * TT + t) << 25) | vid;
                }
            }
        }
        pvid[i] = g;
        pfv[i] = pk;
        if (g != 0xFFFFFFFFu) atomicAdd(&cnt1[g], 1u);
    }
}

// ---------------- single-pass decoupled-lookback exclusive scan ----------------
// MODE 4: in=cnt1 + roibm mask -> lo:prefix(count), hi:prefix(mask ? min(count,32) : 0)
// MODE 3: in=bitmap            -> lo:prefix(popcount)
// status word (self-contained, single u64 => RELAXED atomics suffice):
//   state(2b)<<62 | hi(28b)<<28 | lo(28b); all running sums < 2^28.
// Entries padded to 128B (SSTRIDE) to avoid LLC line contention among pollers.
// Ticket-ordered tile assignment guarantees forward progress.
// Lookback is WAVE-PARALLEL: wave 3's 64 lanes poll 64 predecessors per round.
template <int MODE>
__global__ void __launch_bounds__(256) k_scan_lb(const u32* in, const u32* roibm,
                                                 u32* out_lo, u32* out_hi,
                                                 u64* status, u32* ticket, int n, int ntiles)
{
    __shared__ u64 wsum_sh[4];
    __shared__ u64 excl_sh;
    __shared__ u32 vt_sh;
    int t = threadIdx.x;
    int lane = t & 63, wid = t >> 6;
    if (t == 0) vt_sh = atomicAdd(ticket, 1u);
    __syncthreads();
    int vt = (int)vt_sh;
    int base = vt * TILE + t * VPT;
    u32 v[VPT];
    bool full = (base + VPT <= n);
    if (full) {
        #pragma unroll
        for (int q = 0; q < VPT / 4; q++) {
            uint4 a = *(const uint4*)(in + base + q * 4);
            v[q * 4 + 0] = a.x; v[q * 4 + 1] = a.y; v[q * 4 + 2] = a.z; v[q * 4 + 3] = a.w;
        }
    } else {
        #pragma unroll
        for (int e = 0; e < VPT; e++) { int i = base + e; v[e] = (i < n) ? in[i] : 0u; }
    }
    auto val_of = [&](u32 x, int i) -> u64 {
        if (MODE == 4) {
            u32 cnt = x;
            u32 kept = 0;
            if (cnt) {
                int f = i / C1, lv = i - f * C1;
                int cy = lv / GX1, cx = lv - cy * GX1;
                u32 bit = (roibm[(size_t)f * (GY1 * RBW) + cy * RBW + (cx >> 5)] >> (cx & 31)) & 1u;
                kept = bit ? (cnt < 32u ? cnt : 32u) : 0u;
            }
            return (u64)cnt | ((u64)kept << 32);
        } else {
            return (u64)(u32)__popc(x);
        }
    };
    u64 sum = 0;
    #pragma unroll
    for (int e = 0; e < VPT; e++) sum += val_of(v[e], base + e);
    // wave-level inclusive scan (no barriers)
    u64 ws = sum;
    #pragma unroll
    for (int off = 1; off < 64; off <<= 1) {
        u64 y = __shfl_up(ws, off, 64);
        if (lane >= off) ws += y;
    }
    if (lane == 63) wsum_sh[wid] = ws;
    __syncthreads();
    u64 w0 = wsum_sh[0], w1 = wsum_sh[1], w2 = wsum_sh[2], w3 = wsum_sh[3];
    u64 wexcl = (wid > 0 ? w0 : 0) + (wid > 1 ? w1 : 0) + (wid > 2 ? w2 : 0);
    u64 texcl = wexcl + ws - sum;
    u64 total = w0 + w1 + w2 + w3;
    u32 tlo = (u32)(total & 0xFFFFFFFFull), thi = (u32)(total >> 32);

    if (vt == 0) {
        if (t == 0) {
            __hip_atomic_store(&status[0], (2ull << 62) | ((u64)thi << 28) | (u64)tlo,
                               __ATOMIC_RELAXED, __HIP_MEMORY_SCOPE_AGENT);
            excl_sh = 0;
            if (ntiles == 1) { out_lo[n] = tlo; if (MODE == 4) out_hi[n] = thi; }
        }
    } else if (wid == 3) {      // wave 3: post partial, then lane-parallel lookback
        if (lane == 0)
            __hip_atomic_store(&status[(size_t)vt * SSTRIDE],
                               (1ull << 62) | ((u64)thi << 28) | (u64)tlo,
                               __ATOMIC_RELAXED, __HIP_MEMORY_SCOPE_AGENT);
        u32 elo = 0, ehi = 0;
        int bidx = vt - 1;
        while (true) {
            int idx = bidx - lane;
            u64 s;
            if (idx >= 0) {
                while (true) {
                    s = __hip_atomic_load(&status[(size_t)idx * SSTRIDE], __ATOMIC_RELAXED,
                                          __HIP_MEMORY_SCOPE_AGENT);
                    if ((s >> 62) != 0ull) break;
                    __builtin_amdgcn_s_sleep(1);
                }
            } else {
                s = 2ull << 62;   // virtual inclusive-0 before the beginning
            }
            u64 bal = __ballot((s >> 62) == 2ull);
            u32 clo, chi;
            if (bal) {
                u32 L = (u32)__ffsll((unsigned long long)bal) - 1u;  // nearest state-2
                clo = ((u32)lane <= L) ? (u32)(s & 0xFFFFFFFull) : 0u;
                chi = ((u32)lane <= L) ? (u32)((s >> 28) & 0xFFFFFFFull) : 0u;
            } else {
                clo = (u32)(s & 0xFFFFFFFull);
                chi = (u32)((s >> 28) & 0xFFFFFFFull);
            }
            #pragma unroll
            for (int off = 1; off < 64; off <<= 1) {
                clo += __shfl_xor(clo, off, 64);
                chi += __shfl_xor(chi, off, 64);
            }
            elo += clo; ehi += chi;
            if (bal) break;
            bidx -= 64;
        }
        if (lane == 0) {
            __hip_atomic_store(&status[(size_t)vt * SSTRIDE],
                (2ull << 62) | ((u64)(thi + ehi) << 28) | (u64)(tlo + elo),
                __ATOMIC_RELAXED, __HIP_MEMORY_SCOPE_AGENT);
            excl_sh = (u64)elo | ((u64)ehi << 32);
            if (vt == ntiles - 1) {
                out_lo[n] = tlo + elo;
                if (MODE == 4) out_hi[n] = thi + ehi;
            }
        }
    }
    __syncthreads();
    u64 run = excl_sh + texcl;
    if (full) {
        #pragma unroll
        for (int q = 0; q < VPT / 4; q++) {
            u32 lo_a[4], hi_a[4];
            #pragma unroll
            for (int e = 0; e < 4; e++) {
                lo_a[e] = (u32)run; hi_a[e] = (u32)(run >> 32);
                run += val_of(v[q * 4 + e], base + q * 4 + e);
            }
            *(uint4*)(out_lo + base + q * 4) = make_uint4(lo_a[0], lo_a[1], lo_a[2], lo_a[3]);
            if (MODE == 4)
                *(uint4*)(out_hi + base + q * 4) = make_uint4(hi_a[0], hi_a[1], hi_a[2], hi_a[3]);
        }
    } else {
        for (int e = 0; e < VPT; e++) {
            int i = base + e;
            if (i < n) {
                out_lo[i] = (u32)run;
                if (MODE == 4) out_hi[i] = (u32)(run >> 32);
                run += val_of(v[e], i);
            }
        }
    }
}

// ---------------- stage-1 scatter (starts doubles as cursor; old value = abs pos) ----------------
__global__ void k_scatter(const u32* pvid, int n, u32* starts, u32* ptbuf)
{
    int i = blockIdx.x * blockDim.x + threadIdx.x;
    if (i >= n) return;
    u32 g = pvid[i];
    if (g == 0xFFFFFFFFu) return;
    u32 pos = atomicAdd(&starts[g], 1u);
    ptbuf[pos] = (u32)i;
}

// ---------------- fused: per-cell sort + emit kept points + fine-voxel bitmap ----------------
__global__ void k_emit2(const u32* pfv, const u32* cnt1, const u32* starts, const u32* koffc,
                        const u32* roibm, u32* ptbuf, u32* kept, u32* fvid, u32* bitmap)
{
    int c = blockIdx.x * blockDim.x + threadIdx.x;
    if (c >= NC1) return;
    u32 n = cnt1[c];
    if (!n) return;
    int f = c / C1, lv = c - f * C1;
    int cy = lv / GX1, cx = lv - cy * GX1;
    u32 bit = (roibm[(size_t)f * (GY1 * RBW) + cy * RBW + (cx >> 5)] >> (cx & 31)) & 1u;
    if (!bit) return;
    u32 s0 = starts[c] - n;   // starts was advanced by n during scatter
    // stable order within voxel = ascending point index: insertion sort
    for (u32 a = 1; a < n; a++) {
        u32 v = ptbuf[s0 + a];
        int bp2 = (int)a;
        while (bp2 > 0 && ptbuf[s0 + bp2 - 1] > v) { ptbuf[s0 + bp2] = ptbuf[s0 + bp2 - 1]; bp2--; }
        ptbuf[s0 + bp2] = v;
    }
    u32 m = n < 32u ? n : 32u;
    u32 base = koffc[c];
    for (u32 r = 0; r < m; r++) {
        u32 pidx = ptbuf[s0 + r];
        kept[base + r] = pidx;
        u32 pk = pfv[pidx];
        if (pk != 0xFFFFFFFFu) {
            u32 f2 = pk >> 25, vid = pk & 0x1FFFFFFu;
            atomicOr(&bitmap[f2 * WPF + (vid >> 5)], 1u << (vid & 31));
        }
        fvid[base + r] = pk;
    }
}

// ---------------- insert kept seqs into per-voxel 5-min sorted arrays ----------------
__global__ void k_insert(const u32* fvid, const u32* koffend, const u32* bitmap,
                         const u32* wordpref, u32* slotseq)
{
    u32 i = blockIdx.x * blockDim.x + threadIdx.x;
    u32 Mt = koffend[0];
    if (i >= Mt) return;
    u32 pk = fvid[i];
    if (pk == 0xFFFFFFFFu) return;
    u32 f = pk >> 25, vid = pk & 0x1FFFFFFu;
    u32 gw = f * WPF + (vid >> 5);
    u32 slot = wordpref[gw] - wordpref[f * WPF] +
               (u32)__popc(bitmap[gw] & ((1u << (vid & 31)) - 1u));
    if (slot >= (u32)MAXV) return;
    u32* arr = slotseq + (size_t)(f * MAXV + slot) * KK2;
    u32 val = i;
    #pragma unroll
    for (int j = 0; j < KK2; j++) {
        u32 old = atomicMin(&arr[j], val);
        if (old == 0xFFFFFFFFu) break;     // landed in empty slot
        val = old > val ? old : val;       // carry displaced value
    }
}

// ---------------- per-(frame, roi) selection + output ----------------
__global__ void __launch_bounds__(256) k_output(const float* P, const u32* boxp,
    const u32* bitmap, const u32* wordpref, const u32* slotseq, const u32* kept, float* out)
{
    __shared__ u32 rpref_s[MAXROWS];
    __shared__ u32 ssum[256];
    __shared__ int sidx[NSAMP];
    __shared__ float feat[KK2 * NSAMP][5];
    __shared__ u32 pmf[KK2 * NSAMP];
    __shared__ int sel[NSAMP];
    __shared__ int nsel_s;
    __shared__ u32 M_s;

    int bid = blockIdx.x, tid = threadIdx.x;
    int f = bid / RR, r = bid % RR;
    int b = f / TT, t = f % TT;
    const u32* bp = boxp + bid * 12;
    float bx = __uint_as_float(bp[0]);
    float by = __uint_as_float(bp[1]);
    float cr2 = __uint_as_float(bp[2]);
    float zmax = __uint_as_float(bp[3]);
    int Q1x = (int)bp[7], Q1y = (int)bp[8], irad2 = (int)bp[9];

    const u32* bmf = bitmap + (size_t)f * WPF;
    u32 wp_f0 = wordpref[f * WPF];
    u32 nv2u = wordpref[(f + 1) * WPF] - wp_f0;
    int nv2 = (nv2u > (u32)MAXV) ? MAXV : (int)nv2u;

    int cxlo = Q1x - irad2 + 1; if (cxlo < 0) cxlo = 0;
    int cxhi = Q1x + irad2 - 1; if (cxhi > GX2 - 1) cxhi = GX2 - 1;
    int cylo = Q1y - irad2 + 1; if (cylo < 0) cylo = 0;
    int cyhi = Q1y + irad2 - 1; if (cyhi > GY2 - 1) cyhi = GY2 - 1;
    int ny = cyhi - cylo + 1;
    int nrows = (cxlo <= cxhi && cylo <= cyhi) ? GZ2 * ny : 0;
    if (nrows > MAXROWS) nrows = MAXROWS;

    // phase A: per-row match counts via bitmap popcount (blocked per thread)
    u32 myrpref[RPT];
    u32 lsum = 0;
    #pragma unroll
    for (int e = 0; e < RPT; e++) {
        int ri = tid * RPT + e;
        myrpref[e] = lsum;
        if (ri < nrows) {
            int cz = ri / ny, cy = cylo + (ri - cz * ny);
            u32 vlo = ((u32)cz * GY2 + (u32)cy) * GX2 + (u32)cxlo;
            u32 vhi = vlo + (u32)(cxhi - cxlo);
            u32 gwlo = vlo >> 5, gwhi = vhi >> 5;
            u32 c = 0;
            for (u32 gw = gwlo; gw <= gwhi; gw++) {
                u32 w = bmf[gw];
                u32 lob = (gw == gwlo) ? (vlo & 31u) : 0u;
                u32 hib = (gw == gwhi) ? (vhi & 31u) : 31u;
                u32 m = (hib == 31u ? 0xFFFFFFFFu : ((1u << (hib + 1)) - 1u)) & ~((1u << lob) - 1u);
                c += (u32)__popc(w & m);
            }
            lsum += c;
        }
    }
    ssum[tid] = lsum;
    __syncthreads();
    for (int off = 1; off < 256; off <<= 1) {
        u32 y = (tid >= off) ? ssum[tid - off] : 0;
        __syncthreads();
        ssum[tid] += y;
        __syncthreads();
    }
    u32 texcl = ssum[tid] - lsum;
    if (tid == 255) M_s = ssum[255];
    #pragma unroll
    for (int e = 0; e < RPT; e++) {
        int ri = tid * RPT + e;
        if (ri < MAXROWS) rpref_s[ri] = texcl + myrpref[e];
    }
    __syncthreads();

    u32 M = M_s;
    int nt = (int)(M < (u32)NSAMP ? M : (u32)NSAMP);
    // phase B1: tid-th matched voxel in ascending vid order -> slot via wordpref rank
    if (tid < nt) {
        int lo = 0, hi = nrows - 1;
        while (lo < hi) { int m = (lo + hi + 1) >> 1; if (rpref_s[m] <= (u32)tid) lo = m; else hi = m - 1; }
        u32 rem = (u32)tid - rpref_s[lo];
        int cz = lo / ny, cy = cylo + (lo - cz * ny);
        u32 vlo = ((u32)cz * GY2 + (u32)cy) * GX2 + (u32)cxlo;
        u32 vhi = vlo + (u32)(cxhi - cxlo);
        u32 gwlo = vlo >> 5, gwhi = vhi >> 5;
        int slot = 0;
        for (u32 gw = gwlo; gw <= gwhi; gw++) {
            u32 w = bmf[gw];
            u32 lob = (gw == gwlo) ? (vlo & 31u) : 0u;
            u32 hib = (gw == gwhi) ? (vhi & 31u) : 31u;
            u32 m = (hib == 31u ? 0xFFFFFFFFu : ((1u << (hib + 1)) - 1u)) & ~((1u << lob) - 1u);
            u32 wm = w & m;
            u32 pc = (u32)__popc(wm);
            if (rem < pc) {
                for (u32 k = 0; k < rem; k++) wm &= wm - 1u;
                u32 bit = (u32)__ffs(wm) - 1u;
                slot = (int)(wordpref[f * WPF + gw] - wp_f0 + (u32)__popc(w & ((1u << bit) - 1u)));
                break;
            }
            rem -= pc;
        }
        sidx[tid] = slot;
    }
    __syncthreads();
    // phase B2: top_k false-fill with lowest non-matching slot indices
    if (tid == 0) {
        int c = nt, p = 0, s = 0;
        while (c < NSAMP) {
            if (p < nt && sidx[p] == s) { p++; s++; continue; }
            sidx[c++] = s++;
        }
    }
    __syncthreads();

    // phase C: gather sv; thread mapping is s-major (5 consecutive lanes share one slot's
    // contiguous slotseq words) but feat[] is written in reference flat (k2-major) order.
    for (int j2 = tid; j2 < KK2 * NSAMP; j2 += 256) {
        int s = j2 / KK2, k2 = j2 - s * KK2;
        int j = k2 * NSAMP + s;
        int slot = sidx[s];
        float px = 0.f, py = 0.f, pz = 0.f, pi = 0.f, pt = 0.f;
        if (slot < nv2) {
            u32 seq = slotseq[(size_t)(f * MAXV + slot) * KK2 + k2];
            if (seq != 0xFFFFFFFFu) {
                u32 pidx = kept[seq];
                const float* p = P + (size_t)pidx * 6;
                px = p[1]; py = p[2]; pz = p[3]; pi = p[4]; pt = p[5];
            }
        }
        feat[j][0] = px; feat[j][1] = py; feat[j][2] = pz; feat[j][3] = pi; feat[j][4] = pt;
        float ex = px - bx, ey = py - by;
        pmf[j] = (ex * ex + ey * ey < cr2 && pz <= zmax) ? 1u : 0u;
    }
    __syncthreads();

    // phase D: top_k over pm in flat order
    if (tid == 0) {
        int c = 0;
        for (int j = 0; j < KK2 * NSAMP && c < NSAMP; j++)
            if (pmf[j]) sel[c++] = j;
        nsel_s = c;
    }
    __syncthreads();

    // phase E: write 32 rows x 5 feats
    int obase = ((b * RR + r) * (TT * NSAMP) + t * NSAMP) * 5;
    for (int w = tid; w < NSAMP * 5; w += 256) {
        int row = w / 5, col = w % 5;
        float v = (row < nsel_s) ? feat[sel[row]][col] : 0.f;
        out[obase + w] = v;
    }
}

extern "C" void kernel_launch(void* const* d_in, const int* in_sizes, int n_in,
                              void* d_out, int out_size, void* d_ws, size_t ws_size,
                              hipStream_t stream)
{
    const float* P = (const float*)d_in[0];
    const float* traj = (const float*)d_in[1];
    const float* back = (const float*)d_in[2];
    const unsigned char* vlb = (const unsigned char*)d_in[3];
    float* out = (float*)d_out;
    int N = in_sizes[0] / 6;
    if (N > NMAXP) N = NMAXP;

    char* cur = (char*)d_ws;
    auto carve = [&](size_t bytes) -> char* {
        char* p = cur;
        cur += (bytes + 255) & ~(size_t)255;
        return p;
    };

    // ---- zero zone: cnt1 + roibm + bitmap + scan status + tickets ----
    char* zoneZ = cur;
    u32* cnt1    = (u32*)carve((size_t)NC1 * 4);
    u32* roibm   = (u32*)carve((size_t)NF * GY1 * RBW * 4);
    u32* bitmap  = (u32*)carve((size_t)NF * WPF * 4);
    u64* status  = (u64*)carve((size_t)2 * STN * SSTRIDE * 8);
    u32* tickets = (u32*)carve(64);
    size_t z_bytes = (size_t)(cur - zoneZ);
    // ---- 0xFF zone: slotseq ----
    u32* slotseq = (u32*)carve((size_t)NF * MAXV * KK2 * 4);
    size_t ff_bytes = (size_t)(cur - (char*)slotseq);

    // ---- fully-written by scans / kernels (no init) ----
    u32* starts   = (u32*)carve((size_t)(NC1 + 1) * 4);
    u32* koffc    = (u32*)carve((size_t)(NC1 + 1) * 4);
    u32* wordpref = (u32*)carve((size_t)(NF * WPF + 1) * 4);
    u32* pvid     = (u32*)carve((size_t)NMAXP * 4);
    u32* pfv      = (u32*)carve((size_t)NMAXP * 4);
    u32* ptbuf    = (u32*)carve((size_t)NMAXP * 4);
    u32* boxp     = (u32*)carve((size_t)NF * RR * 12 * 4);
    u32* kept     = (u32*)carve((size_t)NMAXP * 4);
    u32* fvid     = (u32*)carve((size_t)NMAXP * 4);
    if ((size_t)(cur - (char*)d_ws) > ws_size) return;  // insufficient workspace

    k_init<<<1024, 256, 0, stream>>>((u32*)zoneZ, (u32)(z_bytes / 16),
                                     slotseq, (u32)(ff_bytes / 16));

    k_roipts<<<(N + 255) / 256, 256, 0, stream>>>(P, N, traj, back, vlb, boxp, roibm,
                                                  pvid, pfv, cnt1);

    {   // scan 4: cnt1 (+roibm mask) -> starts (count prefix) + koffc (masked capped prefix)
        int n = NC1, nt = (n + TILE - 1) / TILE;
        k_scan_lb<4><<<nt, 256, 0, stream>>>(cnt1, roibm, starts, koffc, status, &tickets[0], n, nt);
    }

    k_scatter<<<(N + 255) / 256, 256, 0, stream>>>(pvid, N, starts, ptbuf);
    k_emit2<<<(NC1 + 255) / 256, 256, 0, stream>>>(pfv, cnt1, starts, koffc, roibm, ptbuf,
                                                   kept, fvid, bitmap);

    {   // scan 3: bitmap -> wordpref (popcount prefix)
        int n = NF * WPF, nt = (n + TILE - 1) / TILE;
        k_scan_lb<3><<<nt, 256, 0, stream>>>(bitmap, nullptr, wordpref, nullptr,
                                             status + (size_t)STN * SSTRIDE, &tickets[1], n, nt);
    }

    k_insert<<<NPAD / 256, 256, 0, stream>>>(fvid, koffc + NC1, bitmap, wordpref, slotseq);
    k_output<<<NF * RR, 256, 0, stream>>>(P, boxp, bitmap, wordpref, slotseq, kept, out);
}